// Round 6
// baseline (470.836 us; speedup 1.0000x reference)
//
#include <hip/hip_runtime.h>
#include <stdint.h>

#define SIZE 65535

typedef __bf16 bf16x8 __attribute__((ext_vector_type(8)));
typedef float floatx4 __attribute__((ext_vector_type(4)));

// ws layout (bf16 elements), FRAGMENT-LINEAR: chunk = tile*64 + lane, 8 elems/chunk.
#define WS_ENCW 0        // [nt8][kt8][lane][8]        -> 32768
#define WS_WIH  32768    // [nt8][g3][kt4][lane][8]    -> 49152
#define WS_WHH  81920    // [nt8][g3][kt4][lane][8]    -> 49152
#define WS_VW   131072   // [nt4][kt4][lane][8]        -> 8192
#define WS_DECW 139264   // [kt8][lane][8] (rows>=10 and kt>=6 zero) -> 4096
#define WS_TOTC 17920    // weight chunks (x8 elems = 143360 shorts)
#define X_WS    143360   // x intermediate, bf16 row-major [65536][128] -> 8388608 shorts

__device__ __forceinline__ unsigned short f2bf(float f) {
    union { float f; unsigned int u; } v; v.f = f;
    unsigned int u = v.u;
    return (unsigned short)((u + 0x7fffu + ((u >> 16) & 1u)) >> 16);
}
__device__ __forceinline__ float sigmf(float x) {
    x = fminf(fmaxf(x, -30.f), 30.f);
    return 1.f / (1.f + __expf(-x));
}
__device__ __forceinline__ float tanhfast(float x) {
    x = fminf(fmaxf(x, -15.f), 15.f);
    float e = __expf(2.f * x);
    return (e - 1.f) / (e + 1.f);
}

union BF8 { bf16x8 v; unsigned short s[8]; };

__device__ __forceinline__ bf16x8 cvt8g(const float* p) {
    float4 a = *reinterpret_cast<const float4*>(p);
    float4 b = *reinterpret_cast<const float4*>(p + 4);
    BF8 r;
    r.s[0] = f2bf(a.x); r.s[1] = f2bf(a.y); r.s[2] = f2bf(a.z); r.s[3] = f2bf(a.w);
    r.s[4] = f2bf(b.x); r.s[5] = f2bf(b.y); r.s[6] = f2bf(b.z); r.s[7] = f2bf(b.w);
    return r.v;
}
__device__ __forceinline__ bf16x8 ld8(const unsigned short* p) {
    return *reinterpret_cast<const bf16x8*>(p);
}
// async global->LDS, 16B/lane; LDS dest = wave-uniform base + lane*16.
__device__ __forceinline__ void glds16(const unsigned short* g, unsigned short* l) {
    __builtin_amdgcn_global_load_lds(
        (const __attribute__((address_space(1))) unsigned int*)g,
        (__attribute__((address_space(3))) unsigned int*)l, 16, 0, 0);
}

// ---------- pre-kernel: f32 weights -> bf16 fragment-linear layout ----------
__global__ __launch_bounds__(256) void cvt_weights(
    const float* __restrict__ enc_w, const float* __restrict__ w_ih,
    const float* __restrict__ w_hh, const float* __restrict__ v_w,
    const float* __restrict__ dec_w, unsigned short* __restrict__ ws) {
    int c = blockIdx.x * 256 + threadIdx.x;
    if (c >= WS_TOTC) return;
    const int lane = c & 63;
    const int l = lane & 15;
    const int q = lane >> 4;
    const float* src; int row, col, stride; bool zero = false;
    if (c < 4096) {                      // enc_w [nt8][kt8]
        int lt = c >> 6; int nt = lt >> 3, kt = lt & 7;
        row = nt * 16 + l; col = kt * 32 + q * 8; src = enc_w; stride = 256;
    } else if (c < 10240) {              // w_ih [nt8][g3][kt4]
        int lt = (c - 4096) >> 6; int nt = lt / 12; int r2 = lt % 12;
        int g = r2 >> 2, kt = r2 & 3;
        row = g * 128 + nt * 16 + l; col = kt * 32 + q * 8; src = w_ih; stride = 128;
    } else if (c < 16384) {              // w_hh
        int lt = (c - 10240) >> 6; int nt = lt / 12; int r2 = lt % 12;
        int g = r2 >> 2, kt = r2 & 3;
        row = g * 128 + nt * 16 + l; col = kt * 32 + q * 8; src = w_hh; stride = 128;
    } else if (c < 17408) {              // v_w [nt4][kt4]
        int lt = (c - 16384) >> 6; int nt = lt >> 2, kt = lt & 3;
        row = nt * 16 + l; col = kt * 32 + q * 8; src = v_w; stride = 128;
    } else {                             // dec_w [kt8], zero rows>=10 / kt>=6
        int kt = (c - 17408) >> 6;
        row = l; col = kt * 32 + q * 8; src = dec_w; stride = 192;
        zero = (l >= 10) || (kt >= 6);
    }
    float4 a, b;
    if (zero) { a = make_float4(0.f,0.f,0.f,0.f); b = a; }
    else {
        const float* p = src + (size_t)row * stride + col;
        a = *reinterpret_cast<const float4*>(p);
        b = *reinterpret_cast<const float4*>(p + 4);
    }
    unsigned short* d = ws + (size_t)c * 8;
    d[0]=f2bf(a.x); d[1]=f2bf(a.y); d[2]=f2bf(a.z); d[3]=f2bf(a.w);
    d[4]=f2bf(b.x); d[5]=f2bf(b.y); d[6]=f2bf(b.z); d[7]=f2bf(b.w);
}

// ---------- pass 1: X = relu(OBS @ enc_w^T + enc_b) -> x bf16 in ws ----------
// 512-thread blocks (8 waves), 256 rows/block: staging amortized over 2x rows,
// 2x waves/CU vs R5. Col-HALF split (32KB LDS) + XCD swizzle (obs re-read is
// an L2 hit). Swapped operands -> direct ushort4 x stores.
__global__ __launch_bounds__(512, 4) void pass1_enc(
    const float* __restrict__ obs,    // [SIZE,256] f32
    const float* __restrict__ enc_b,  // [128] f32
    const unsigned short* __restrict__ wsw,
    unsigned short* __restrict__ xws) // x bf16 [65536][128]
{
    __shared__ __align__(16) unsigned short wenc[16384];   // 32 KB (half of enc_w)

    const int tid  = threadIdx.x;
    const int wave = tid >> 6;
    const int lane = tid & 63;
    const int l15  = lane & 15;
    const int quad = lane >> 4;
    // XCD swizzle: grid 512 = 8 xcd x 64 slots; tile = xcd*32 + slot/2
    const int b    = blockIdx.x;
    const int xcd  = b & 7;
    const int s    = b >> 3;
    const int tile = xcd * 32 + (s >> 1);   // 0..255, 256 rows each
    const int half = s & 1;
    const int wrow0 = tile * 256 + wave * 32;

    // stage enc_w half: 2048 lane-chunks, 4 per thread (async)
#pragma unroll
    for (int st = 0; st < 4; ++st) {
        const int c = st * 512 + tid;
        glds16(wsw + WS_ENCW + half * 16384 + (size_t)c * 8, wenc + (size_t)c * 8);
    }

    int rA0 = wrow0 + l15;      rA0 = (rA0 < SIZE) ? rA0 : (SIZE - 1);
    int rA1 = wrow0 + 16 + l15; rA1 = (rA1 < SIZE) ? rA1 : (SIZE - 1);

    // obs B-fragments (row=l15, k=quad*8..): full K=256
    bf16x8 bo[2][8];
    {
        const float* o0 = obs + (size_t)rA0 * 256;
        const float* o1 = obs + (size_t)rA1 * 256;
#pragma unroll
        for (int kt = 0; kt < 8; ++kt) {
            bo[0][kt] = cvt8g(o0 + kt * 32 + quad * 8);
            bo[1][kt] = cvt8g(o1 + kt * 32 + quad * 8);
        }
    }
    __syncthreads();   // staging + own loads drained

#pragma unroll 1
    for (int ntl = 0; ntl < 4; ++ntl) {
        floatx4 d0 = floatx4{0.f,0.f,0.f,0.f}, d1 = d0;
#pragma unroll
        for (int kt = 0; kt < 8; ++kt) {
            bf16x8 a = ld8(&wenc[(ntl * 8 + kt) * 512 + lane * 8]);
            d0 = __builtin_amdgcn_mfma_f32_16x16x32_bf16(a, bo[0][kt], d0, 0, 0, 0);
            d1 = __builtin_amdgcn_mfma_f32_16x16x32_bf16(a, bo[1][kt], d1, 0, 0, 0);
        }
        const int col0 = half * 64 + ntl * 16 + quad * 4;
        const float4 ebv = *reinterpret_cast<const float4*>(enc_b + col0);
        const float eb[4] = {ebv.x, ebv.y, ebv.z, ebv.w};
#pragma unroll
        for (int m = 0; m < 2; ++m) {
            const int grow = wrow0 + m * 16 + l15;
            if (grow < SIZE) {
                const floatx4& d = m ? d1 : d0;
                ushort4 pk;
                pk.x = f2bf(fmaxf(d[0] + eb[0], 0.f));
                pk.y = f2bf(fmaxf(d[1] + eb[1], 0.f));
                pk.z = f2bf(fmaxf(d[2] + eb[2], 0.f));
                pk.w = f2bf(fmaxf(d[3] + eb[3], 0.f));
                *reinterpret_cast<ushort4*>(xws + (size_t)grow * 128 + col0) = pk;
            }
        }
    }
}

// ---------- pass 2: GRU cell -> h_out f32 (final output region) ----------
// 512-thread blocks, 256 rows/block, col-quarter split (48KB LDS) + XCD
// swizzle. launch_bounds(512,6): VGPR cap 85 (R5 used 84 for identical math)
// -> 3 blocks/CU x 8 waves = 24 waves/CU (vs 8 in R5). Grouped full-line
// h stores kept.
__global__ __launch_bounds__(512, 6) void pass2_gru(
    const float* __restrict__ hid,    // [SIZE,128] f32
    const float* __restrict__ b_ih,   // [384] f32
    const float* __restrict__ b_hh,   // [384] f32
    const unsigned short* __restrict__ wsw,
    const unsigned short* __restrict__ xws,
    float* __restrict__ out_h)        // [SIZE,128] f32
{
    __shared__ __align__(16) unsigned short wq[24576];   // 48 KB: [ih|hh] x [2ntL][3g][4kt]

    const int tid  = threadIdx.x;
    const int wave = tid >> 6;
    const int lane = tid & 63;
    const int l15  = lane & 15;
    const int quad = lane >> 4;
    // XCD swizzle: grid 1024 = 8 xcd x 128 slots; tile = xcd*32 + slot/4
    const int b    = blockIdx.x;
    const int xcd  = b & 7;
    const int s    = b >> 3;
    const int tile = xcd * 32 + (s >> 2);   // 0..255, 256 rows each
    const int q    = s & 3;
    const int wrow0 = tile * 256 + wave * 32;

    // stage 48 frag-slots (3072 lane-chunks, 6 per thread)
#pragma unroll
    for (int st = 0; st < 6; ++st) {
        const int c = st * 512 + tid;          // 0..3071
        const int f = c >> 6, li = c & 63;
        int ff = (f < 24) ? f : f - 24;
        const int ntL = ff / 12, rm = ff % 12;
        const int g = rm >> 2, kt = rm & 3;
        const int gidx = (((q * 2 + ntL) * 3 + g) * 4 + kt);
        const unsigned short* src = wsw + ((f < 24) ? WS_WIH : WS_WHH)
                                        + (size_t)gidx * 512 + li * 8;
        glds16(src, wq + (size_t)c * 8);
    }

    int rA0 = wrow0 + l15;      rA0 = (rA0 < SIZE) ? rA0 : (SIZE - 1);
    int rA1 = wrow0 + 16 + l15; rA1 = (rA1 < SIZE) ? rA1 : (SIZE - 1);

    bf16x8 xb[2][4], hb[2][4];
#pragma unroll
    for (int kt = 0; kt < 4; ++kt) {
        xb[0][kt] = ld8(xws + (size_t)rA0 * 128 + kt * 32 + quad * 8);
        xb[1][kt] = ld8(xws + (size_t)rA1 * 128 + kt * 32 + quad * 8);
        hb[0][kt] = cvt8g(hid + (size_t)rA0 * 128 + kt * 32 + quad * 8);
        hb[1][kt] = cvt8g(hid + (size_t)rA1 * 128 + kt * 32 + quad * 8);
    }
    __syncthreads();

    float ho[2][2][4];   // [ntL][m][r] — all indices compile-time (full unroll)
#pragma unroll
    for (int ntL = 0; ntL < 2; ++ntL) {
        const int oc0 = q * 32 + ntL * 16 + quad * 4;
        floatx4 gi[3][2], gh[3][2];
#pragma unroll
        for (int g = 0; g < 3; ++g) {
            gi[g][0] = floatx4{0.f,0.f,0.f,0.f}; gi[g][1] = gi[g][0];
            gh[g][0] = gi[g][0]; gh[g][1] = gi[g][0];
        }
#pragma unroll
        for (int g = 0; g < 3; ++g)
#pragma unroll
            for (int kt = 0; kt < 4; ++kt) {
                bf16x8 ai = ld8(&wq[((ntL * 3 + g) * 4 + kt) * 512 + lane * 8]);
                bf16x8 ah = ld8(&wq[12288 + ((ntL * 3 + g) * 4 + kt) * 512 + lane * 8]);
                gi[g][0] = __builtin_amdgcn_mfma_f32_16x16x32_bf16(ai, xb[0][kt], gi[g][0], 0, 0, 0);
                gi[g][1] = __builtin_amdgcn_mfma_f32_16x16x32_bf16(ai, xb[1][kt], gi[g][1], 0, 0, 0);
                gh[g][0] = __builtin_amdgcn_mfma_f32_16x16x32_bf16(ah, hb[0][kt], gh[g][0], 0, 0, 0);
                gh[g][1] = __builtin_amdgcn_mfma_f32_16x16x32_bf16(ah, hb[1][kt], gh[g][1], 0, 0, 0);
            }
        const float4 birv = *reinterpret_cast<const float4*>(b_ih + oc0);
        const float4 bizv = *reinterpret_cast<const float4*>(b_ih + 128 + oc0);
        const float4 binv = *reinterpret_cast<const float4*>(b_ih + 256 + oc0);
        const float4 bhrv = *reinterpret_cast<const float4*>(b_hh + oc0);
        const float4 bhzv = *reinterpret_cast<const float4*>(b_hh + 128 + oc0);
        const float4 bhnv = *reinterpret_cast<const float4*>(b_hh + 256 + oc0);
        const float bir[4] = {birv.x, birv.y, birv.z, birv.w};
        const float biz[4] = {bizv.x, bizv.y, bizv.z, bizv.w};
        const float bin[4] = {binv.x, binv.y, binv.z, binv.w};
        const float bhr[4] = {bhrv.x, bhrv.y, bhrv.z, bhrv.w};
        const float bhz[4] = {bhzv.x, bhzv.y, bhzv.z, bhzv.w};
        const float bhn[4] = {bhnv.x, bhnv.y, bhnv.z, bhnv.w};
#pragma unroll
        for (int m = 0; m < 2; ++m) {
            const int grow = wrow0 + m * 16 + l15;
            const int rowc = (grow < SIZE) ? grow : (SIZE - 1);
            const float4 hpv = *reinterpret_cast<const float4*>(hid + (size_t)rowc * 128 + oc0);
            const float hp[4] = {hpv.x, hpv.y, hpv.z, hpv.w};
#pragma unroll
            for (int r = 0; r < 4; ++r) {
                float rg = sigmf(gi[0][m][r] + bir[r] + gh[0][m][r] + bhr[r]);
                float zg = sigmf(gi[1][m][r] + biz[r] + gh[1][m][r] + bhz[r]);
                float ng = tanhfast(gi[2][m][r] + bin[r] + rg * (gh[2][m][r] + bhn[r]));
                ho[ntL][m][r] = (1.f - zg) * ng + zg * hp[r];
            }
        }
    }
    // grouped stores: per row, the wave writes q*32..q*32+32 = one full 128B line
#pragma unroll
    for (int m = 0; m < 2; ++m) {
        const int grow = wrow0 + m * 16 + l15;
        if (grow < SIZE) {
#pragma unroll
            for (int ntL = 0; ntL < 2; ++ntL) {
                const int oc0 = q * 32 + ntL * 16 + quad * 4;
                *reinterpret_cast<float4*>(out_h + (size_t)grow * 128 + oc0) =
                    make_float4(ho[ntL][m][0], ho[ntL][m][1], ho[ntL][m][2], ho[ntL][m][3]);
            }
        }
    }
}

// ---------- pass 3: V = relu(H@v_w^T+v_b); OUT = [H|V]@dec_w^T + dec_b ----------
// 512-thread blocks, 256 rows/block; weights 24KB + per-wave sV/sO -> 71.5KB,
// 2 blocks/CU x 8 waves = 16 waves/CU.
__global__ __launch_bounds__(512, 4) void pass3_vdec(
    const float* __restrict__ hsrc,   // out_h [SIZE,128] f32 (from pass 2)
    const float* __restrict__ v_b,    // [64] f32
    const float* __restrict__ dec_b,  // [10] f32
    const unsigned short* __restrict__ wsw,
    float* __restrict__ out)          // [SIZE*10] f32
{
    __shared__ __align__(16) unsigned short wv[8192];    // 16 KB [4nt][4kt]
    __shared__ __align__(16) unsigned short wdec[4096];  // 8 KB [8kt] (6 used)
    __shared__ __align__(16) unsigned short sV[8][32][72];
    __shared__ __align__(16) float sO[8][32][10];

    const int tid  = threadIdx.x;
    const int wave = tid >> 6;
    const int lane = tid & 63;
    const int l15  = lane & 15;
    const int quad = lane >> 4;
    const int wrow0 = blockIdx.x * 256 + wave * 32;

#pragma unroll
    for (int st = 0; st < 2; ++st) {
        const int c = st * 512 + tid;          // 0..1023
        glds16(wsw + WS_VW + (size_t)c * 8, wv + (size_t)c * 8);
    }
    {
        const int c = tid;                     // 0..511
        glds16(wsw + WS_DECW + (size_t)c * 8, wdec + (size_t)c * 8);
    }

    int rA0 = wrow0 + l15;      rA0 = (rA0 < SIZE) ? rA0 : (SIZE - 1);
    int rA1 = wrow0 + 16 + l15; rA1 = (rA1 < SIZE) ? rA1 : (SIZE - 1);

    bf16x8 ha[2][4];
#pragma unroll
    for (int kt = 0; kt < 4; ++kt) {
        ha[0][kt] = cvt8g(hsrc + (size_t)rA0 * 128 + kt * 32 + quad * 8);
        ha[1][kt] = cvt8g(hsrc + (size_t)rA1 * 128 + kt * 32 + quad * 8);
    }
    __syncthreads();

    // V
#pragma unroll 1
    for (int nt = 0; nt < 4; ++nt) {
        floatx4 a0 = floatx4{0.f,0.f,0.f,0.f}, a1 = a0;
#pragma unroll
        for (int kt = 0; kt < 4; ++kt) {
            bf16x8 b = ld8(&wv[(nt * 4 + kt) * 512 + lane * 8]);
            a0 = __builtin_amdgcn_mfma_f32_16x16x32_bf16(ha[0][kt], b, a0, 0, 0, 0);
            a1 = __builtin_amdgcn_mfma_f32_16x16x32_bf16(ha[1][kt], b, a1, 0, 0, 0);
        }
        const float bias = v_b[nt * 16 + l15];
#pragma unroll
        for (int r = 0; r < 4; ++r) {
            sV[wave][quad * 4 + r][nt * 16 + l15]      = f2bf(fmaxf(a0[r] + bias, 0.f));
            sV[wave][16 + quad * 4 + r][nt * 16 + l15] = f2bf(fmaxf(a1[r] + bias, 0.f));
        }
    }
    // per-wave LDS producer->consumer; no block barrier needed

    // DEC
    {
        floatx4 d0 = floatx4{0.f,0.f,0.f,0.f}, d1 = d0;
#pragma unroll
        for (int kt = 0; kt < 6; ++kt) {
            bf16x8 b = ld8(&wdec[kt * 512 + lane * 8]);
            bf16x8 a0 = (kt < 4) ? ha[0][kt] : ld8(&sV[wave][l15][(kt - 4) * 32 + quad * 8]);
            bf16x8 a1 = (kt < 4) ? ha[1][kt] : ld8(&sV[wave][16 + l15][(kt - 4) * 32 + quad * 8]);
            d0 = __builtin_amdgcn_mfma_f32_16x16x32_bf16(a0, b, d0, 0, 0, 0);
            d1 = __builtin_amdgcn_mfma_f32_16x16x32_bf16(a1, b, d1, 0, 0, 0);
        }
        if (l15 < 10) {
            const float bias = dec_b[l15];
#pragma unroll
            for (int r = 0; r < 4; ++r) {
                sO[wave][quad * 4 + r][l15]      = d0[r] + bias;
                sO[wave][16 + quad * 4 + r][l15] = d1[r] + bias;
            }
        }
#pragma unroll
        for (int j = 0; j < 5; ++j) {
            int idx = j * 64 + lane;          // 0..319
            int row = idx / 10, col = idx % 10;
            int grow = wrow0 + row;
            if (grow < SIZE)
                out[(size_t)grow * 10 + col] = sO[wave][row][col];
        }
    }
}

extern "C" void kernel_launch(void* const* d_in, const int* in_sizes, int n_in,
                              void* d_out, int out_size, void* d_ws, size_t ws_size,
                              hipStream_t stream) {
    const float* obs   = (const float*)d_in[0];
    const float* hid   = (const float*)d_in[1];
    const float* enc_w = (const float*)d_in[2];
    const float* enc_b = (const float*)d_in[3];
    const float* w_ih  = (const float*)d_in[4];
    const float* w_hh  = (const float*)d_in[5];
    const float* b_ih  = (const float*)d_in[6];
    const float* b_hh  = (const float*)d_in[7];
    // d_in[8..19]: dead code (bi-GRU / hard attention / q,k) — unused.
    const float* v_w   = (const float*)d_in[20];
    const float* v_b   = (const float*)d_in[21];
    const float* dec_w = (const float*)d_in[22];
    const float* dec_b = (const float*)d_in[23];
    unsigned short* wsw = (unsigned short*)d_ws;
    unsigned short* xws = wsw + X_WS;
    float* out   = (float*)d_out;
    float* out_h = out + (size_t)SIZE * 10;

    hipLaunchKernelGGL(cvt_weights, dim3((WS_TOTC + 255) / 256), dim3(256), 0, stream,
                       enc_w, w_ih, w_hh, v_w, dec_w, wsw);
    // 512 = 8 XCD x 64 slots; slot pairs = (tile of 256 rows, half)
    hipLaunchKernelGGL(pass1_enc, dim3(512), dim3(512), 0, stream,
                       obs, enc_b, wsw, xws);
    // 1024 = 8 XCD x 128 slots; slot quads = (tile of 256 rows, quarter)
    hipLaunchKernelGGL(pass2_gru, dim3(1024), dim3(512), 0, stream,
                       hid, b_ih, b_hh, wsw, xws, out_h);
    hipLaunchKernelGGL(pass3_vdec, dim3(256), dim3(512), 0, stream,
                       out_h, v_b, dec_b, wsw, out);
}

// Round 7
// 219.382 us; speedup vs baseline: 2.1462x; 2.1462x over previous
//
#include <hip/hip_runtime.h>
#include <stdint.h>

#define SIZE 65535

typedef __bf16 bf16x8 __attribute__((ext_vector_type(8)));
typedef float floatx4 __attribute__((ext_vector_type(4)));

// ws layout (bf16 elements), FRAGMENT-LINEAR: chunk = tile*64 + lane, 8 elems/chunk.
#define WS_ENCW 0        // [nt8][kt8][lane][8]        -> 32768
#define WS_WIH  32768    // [nt8][g3][kt4][lane][8]    -> 49152
#define WS_WHH  81920    // [nt8][g3][kt4][lane][8]    -> 49152
#define WS_VW   131072   // [nt4][kt4][lane][8]        -> 8192
#define WS_DECW 139264   // [kt6][lane][8] (rows>=10 zero) -> 3072
#define WS_TOTC 17792    // total chunks (x64x8 elems = 142336)

// manual round-to-nearest-even (kept for cvt_weights only; main kernel uses
// native __bf16 casts -> hardware cvt, ~4x fewer VALU ops)
__device__ __forceinline__ unsigned short f2bf(float f) {
    union { float f; unsigned int u; } v; v.f = f;
    unsigned int u = v.u;
    return (unsigned short)((u + 0x7fffu + ((u >> 16) & 1u)) >> 16);
}
__device__ __forceinline__ unsigned short f2bfn(float f) {
    union { __bf16 h; unsigned short s; } u; u.h = (__bf16)f;
    return u.s;
}
__device__ __forceinline__ float bf2f(unsigned short b) {
    union { unsigned int u; float f; } v; v.u = ((unsigned int)b) << 16;
    return v.f;
}
__device__ __forceinline__ float sigmf(float x) {
    x = fminf(fmaxf(x, -30.f), 30.f);
    return 1.f / (1.f + __expf(-x));
}
__device__ __forceinline__ float tanhfast(float x) {
    x = fminf(fmaxf(x, -15.f), 15.f);
    float e = __expf(2.f * x);
    return (e - 1.f) / (e + 1.f);
}

// native-cast vector convert: 8 f32 -> bf16x8 (hardware cvt, not bit-twiddle)
__device__ __forceinline__ bf16x8 cvt8g(const float* p) {
    float4 a = *reinterpret_cast<const float4*>(p);
    float4 b = *reinterpret_cast<const float4*>(p + 4);
    bf16x8 r;
    r[0] = (__bf16)a.x; r[1] = (__bf16)a.y; r[2] = (__bf16)a.z; r[3] = (__bf16)a.w;
    r[4] = (__bf16)b.x; r[5] = (__bf16)b.y; r[6] = (__bf16)b.z; r[7] = (__bf16)b.w;
    return r;
}
__device__ __forceinline__ bf16x8 ld8(const unsigned short* p) {
    return *reinterpret_cast<const bf16x8*>(p);
}

// async global->LDS, 16B per lane, no VGPR destination.
__device__ __forceinline__ void glds16(const unsigned short* g, unsigned short* l) {
    __builtin_amdgcn_global_load_lds(
        (const __attribute__((address_space(1))) unsigned int*)g,
        (__attribute__((address_space(3))) unsigned int*)l, 16, 0, 0);
}

// stage nfrags contiguous 1KB fragments; waves split the slots
__device__ __forceinline__ void stage_seq(unsigned short* dst, const unsigned short* src,
                                          int nfrags, int wave, int lane) {
    for (int s = wave; s < nfrags; s += 4)
        glds16(src + s * 512 + lane * 8, dst + s * 512);
}
// stage one GRU chunk ng = nt*3+g: slots 0..3 = w_ih kt0..3, slots 4..7 = w_hh kt0..3
__device__ __forceinline__ void stage_gru(unsigned short* dst, const unsigned short* wsw,
                                          int ng, int wave, int lane) {
    const int fo = (ng * 4 + wave) * 512 + lane * 8;
    glds16(wsw + WS_WIH + fo, dst + wave * 512);
    glds16(wsw + WS_WHH + fo, dst + (4 + wave) * 512);
}

// ---------- pre-kernel: f32 weights -> bf16 fragment-linear layout ----------
__global__ __launch_bounds__(256) void cvt_weights(
    const float* __restrict__ enc_w, const float* __restrict__ w_ih,
    const float* __restrict__ w_hh, const float* __restrict__ v_w,
    const float* __restrict__ dec_w, unsigned short* __restrict__ ws) {
    int c = blockIdx.x * 256 + threadIdx.x;
    if (c >= WS_TOTC) return;
    const int lane = c & 63;
    const int l = lane & 15;
    const int q = lane >> 4;
    const float* src; int row, col, stride; bool zero = false;
    if (c < 4096) {                      // enc_w [nt8][kt8]
        int lt = c >> 6; int nt = lt >> 3, kt = lt & 7;
        row = nt * 16 + l; col = kt * 32 + q * 8; src = enc_w; stride = 256;
    } else if (c < 10240) {              // w_ih [nt8][g3][kt4]
        int lt = (c - 4096) >> 6; int nt = lt / 12; int r2 = lt % 12;
        int g = r2 >> 2, kt = r2 & 3;
        row = g * 128 + nt * 16 + l; col = kt * 32 + q * 8; src = w_ih; stride = 128;
    } else if (c < 16384) {              // w_hh
        int lt = (c - 10240) >> 6; int nt = lt / 12; int r2 = lt % 12;
        int g = r2 >> 2, kt = r2 & 3;
        row = g * 128 + nt * 16 + l; col = kt * 32 + q * 8; src = w_hh; stride = 128;
    } else if (c < 17408) {              // v_w [nt4][kt4]
        int lt = (c - 16384) >> 6; int nt = lt >> 2, kt = lt & 3;
        row = nt * 16 + l; col = kt * 32 + q * 8; src = v_w; stride = 128;
    } else {                             // dec_w [kt6], zero-pad rows 10..15
        int kt = (c - 17408) >> 6;
        row = l; col = kt * 32 + q * 8; src = dec_w; stride = 192;
        zero = (l >= 10);
    }
    float4 a, b;
    if (zero) { a = make_float4(0.f,0.f,0.f,0.f); b = a; }
    else {
        const float* p = src + (size_t)row * stride + col;
        a = *reinterpret_cast<const float4*>(p);
        b = *reinterpret_cast<const float4*>(p + 4);
    }
    unsigned short* d = ws + (size_t)c * 8;
    d[0]=f2bf(a.x); d[1]=f2bf(a.y); d[2]=f2bf(a.z); d[3]=f2bf(a.w);
    d[4]=f2bf(b.x); d[5]=f2bf(b.y); d[6]=f2bf(b.z); d[7]=f2bf(b.w);
}

// ---------- main fused kernel (R2 structure: stage -> compute -> syncthreads) ----------
// THIS ROUND vs R2 (74us): (a) all f32->bf16 conversions via native __bf16
// casts (hardware cvt; R2's manual rounding was ~4 VALU/elem across ~250
// elems/wave), (b) sV/sO overlay the dead sA region + h_out store moved
// before phase 3 -> LDS 74.75KB -> 50KB -> 3 blocks/CU (12 waves/CU vs 8),
// launch_bounds(256,3) caps VGPR at 170 >= R2's 128 demand (no R6 spill).
// Sync structure and chunk schedule byte-identical to R2.
__global__ __launch_bounds__(256, 3) void attn_critic_kernel(
    const float* __restrict__ obs,    // [SIZE,256] f32
    const float* __restrict__ hid,    // [SIZE,128] f32
    const float* __restrict__ enc_b,  // [128] f32
    const float* __restrict__ b_ih,   // [384] f32
    const float* __restrict__ b_hh,   // [384] f32
    const float* __restrict__ v_b,    // [64] f32
    const float* __restrict__ dec_b,  // [10] f32
    const unsigned short* __restrict__ wsw,  // bf16 fragment-linear weights
    float* __restrict__ out)          // [SIZE*10] ++ [SIZE*128] f32
{
    // weight ring: 2 x 8KB (8 fragment slots each)
    __shared__ __align__(16) unsigned short wbuf[2][4096];
    // per-wave pool: sA [32][136]; sV/sO overlay it after h_out is stored
    __shared__ __align__(16) unsigned short pool[4][4352];

    const int tid  = threadIdx.x;
    const int wave = tid >> 6;
    const int lane = tid & 63;
    const int l15  = lane & 15;
    const int quad = lane >> 4;
    const int wrow0 = (blockIdx.x * 4 + wave) * 32;

    unsigned short (*sA)[136] = (unsigned short(*)[136])&pool[wave][0];  // [32][136]
    unsigned short (*sV)[72]  = (unsigned short(*)[72]) &pool[wave][0];  // [32][72] overlay
    float* sO = (float*)&pool[wave][2304];                               // [32][10] overlay

    int rA0 = wrow0 + l15;      rA0 = (rA0 < SIZE) ? rA0 : (SIZE - 1);
    int rA1 = wrow0 + 16 + l15; rA1 = (rA1 < SIZE) ? rA1 : (SIZE - 1);

    // ---- stage phase-1 chunk 0; its latency hides under the obs/hid prefetch ----
    stage_seq(wbuf[0], wsw + WS_ENCW, 8, wave, lane);

    // ---- prefetch obs + hid A-fragments ----
    bf16x8 aob[2][8], hf[2][4];
    {
        const float* o0 = obs + (size_t)rA0 * 256;
        const float* o1 = obs + (size_t)rA1 * 256;
#pragma unroll
        for (int kt = 0; kt < 8; ++kt) {
            aob[0][kt] = cvt8g(o0 + kt * 32 + quad * 8);
            aob[1][kt] = cvt8g(o1 + kt * 32 + quad * 8);
        }
        const float* h0 = hid + (size_t)rA0 * 128;
        const float* h1 = hid + (size_t)rA1 * 128;
#pragma unroll
        for (int kt = 0; kt < 4; ++kt) {
            hf[0][kt] = cvt8g(h0 + kt * 32 + quad * 8);
            hf[1][kt] = cvt8g(h1 + kt * 32 + quad * 8);
        }
    }
    __builtin_amdgcn_sched_barrier(0);
    __syncthreads();   // chunk 0 staged

    // ---- Phase 1: X = relu(OBS @ enc_w^T + enc_b), chunks 0..7 ----
#pragma unroll 1
    for (int nt = 0; nt < 8; ++nt) {
        const int cur = nt & 1;
        if (nt < 7) stage_seq(wbuf[cur ^ 1], wsw + WS_ENCW + (nt + 1) * 4096, 8, wave, lane);
        else        stage_gru(wbuf[cur ^ 1], wsw, 0, wave, lane);   // phase-2 chunk 0
        const float bias = enc_b[nt * 16 + l15];
        floatx4 a0 = floatx4{0.f,0.f,0.f,0.f}, a1 = a0;
#pragma unroll
        for (int kt = 0; kt < 8; ++kt) {
            bf16x8 b = ld8(&wbuf[cur][kt * 512 + lane * 8]);
            a0 = __builtin_amdgcn_mfma_f32_16x16x32_bf16(aob[0][kt], b, a0, 0, 0, 0);
            a1 = __builtin_amdgcn_mfma_f32_16x16x32_bf16(aob[1][kt], b, a1, 0, 0, 0);
        }
#pragma unroll
        for (int r = 0; r < 4; ++r) {
            sA[quad * 4 + r][nt * 16 + l15]      = f2bfn(fmaxf(a0[r] + bias, 0.f));
            sA[16 + quad * 4 + r][nt * 16 + l15] = f2bfn(fmaxf(a1[r] + bias, 0.f));
        }
        __syncthreads();   // staged chunk ready; all reads of wbuf[cur] done
    }

    bf16x8 xf[2][4];
#pragma unroll
    for (int kt = 0; kt < 4; ++kt) {
        xf[0][kt] = ld8(&sA[l15][kt * 32 + quad * 8]);
        xf[1][kt] = ld8(&sA[16 + l15][kt * 32 + quad * 8]);
    }

    // ---- Phase 2: GRU cell (h_out bf16 -> sA cols 0..127), chunks ng=0..23 ----
#pragma unroll 1
    for (int nt = 0; nt < 8; ++nt) {
        const int nr = nt * 16 + l15;
        // hprev + biases issued at loop top (L1/L2-hot), consumed after MFMA
        float hp[2][4];
#pragma unroll
        for (int m = 0; m < 2; ++m)
#pragma unroll
            for (int r = 0; r < 4; ++r) {
                const int grow = wrow0 + m * 16 + quad * 4 + r;
                const int rowc = (grow < SIZE) ? grow : (SIZE - 1);
                hp[m][r] = hid[(size_t)rowc * 128 + nr];
            }
        const float bir_ = b_ih[nr], biz_ = b_ih[nr + 128], bin_ = b_ih[nr + 256];
        const float bhr_ = b_hh[nr], bhz_ = b_hh[nr + 128], bhn_ = b_hh[nr + 256];
        floatx4 gi[3][2], gh[3][2];
#pragma unroll
        for (int g = 0; g < 3; ++g) {
            gi[g][0] = floatx4{0.f,0.f,0.f,0.f}; gi[g][1] = gi[g][0];
            gh[g][0] = gi[g][0]; gh[g][1] = gi[g][0];
        }
#pragma unroll
        for (int g = 0; g < 3; ++g) {
            const int cur = (nt + g) & 1;
            const int ng = nt * 3 + g + 1;
            if (ng < 24) stage_gru(wbuf[cur ^ 1], wsw, ng, wave, lane);
            else         stage_seq(wbuf[cur ^ 1], wsw + WS_VW, 4, wave, lane); // phase-3 chunk 0
#pragma unroll
            for (int kt = 0; kt < 4; ++kt) {
                bf16x8 bi = ld8(&wbuf[cur][kt * 512 + lane * 8]);
                bf16x8 bh = ld8(&wbuf[cur][(4 + kt) * 512 + lane * 8]);
                gi[g][0] = __builtin_amdgcn_mfma_f32_16x16x32_bf16(xf[0][kt], bi, gi[g][0], 0, 0, 0);
                gi[g][1] = __builtin_amdgcn_mfma_f32_16x16x32_bf16(xf[1][kt], bi, gi[g][1], 0, 0, 0);
                gh[g][0] = __builtin_amdgcn_mfma_f32_16x16x32_bf16(hf[0][kt], bh, gh[g][0], 0, 0, 0);
                gh[g][1] = __builtin_amdgcn_mfma_f32_16x16x32_bf16(hf[1][kt], bh, gh[g][1], 0, 0, 0);
            }
            __syncthreads();
        }
#pragma unroll
        for (int m = 0; m < 2; ++m)
#pragma unroll
            for (int r = 0; r < 4; ++r) {
                float rg = sigmf(gi[0][m][r] + bir_ + gh[0][m][r] + bhr_);
                float zg = sigmf(gi[1][m][r] + biz_ + gh[1][m][r] + bhz_);
                float ng2 = tanhfast(gi[2][m][r] + bin_ + rg * (gh[2][m][r] + bhn_));
                float ho = (1.f - zg) * ng2 + zg * hp[m][r];
                sA[m * 16 + quad * 4 + r][nr] = f2bfn(ho);
            }
    }

    // ---- capture h_out fragments, then store h_out (sA dies; sV/sO overlay) ----
    bf16x8 af[2][4];
#pragma unroll
    for (int kt = 0; kt < 4; ++kt) {
        af[0][kt] = ld8(&sA[l15][kt * 32 + quad * 8]);
        af[1][kt] = ld8(&sA[16 + l15][kt * 32 + quad * 8]);
    }
    {
        float* out_h = out + (size_t)SIZE * 10;
#pragma unroll 1
        for (int it = 0; it < 16; ++it) {
            int idx = it * 256 + lane * 4;   // over [32][128]
            int rr = idx >> 7, cc = idx & 127;
            int grow = wrow0 + rr;
            if (grow < SIZE) {
                float2 p0 = make_float2(bf2f(sA[rr][cc]),     bf2f(sA[rr][cc + 1]));
                float2 p1 = make_float2(bf2f(sA[rr][cc + 2]), bf2f(sA[rr][cc + 3]));
                float* dst = out_h + (size_t)grow * 128 + cc;
                *reinterpret_cast<float2*>(dst)     = p0;
                *reinterpret_cast<float2*>(dst + 2) = p1;
            }
        }
    }

    // ---- Phase 3: V = relu(H_OUT @ v_w^T + v_b) -> sV (overlay), chunks nt=0..3 ----
#pragma unroll 1
    for (int nt = 0; nt < 4; ++nt) {
        const int cur = nt & 1;
        if (nt < 3) stage_seq(wbuf[cur ^ 1], wsw + WS_VW + (nt + 1) * 2048, 4, wave, lane);
        else        stage_seq(wbuf[cur ^ 1], wsw + WS_DECW, 6, wave, lane);  // phase-4 chunk
        const float bias = v_b[nt * 16 + l15];
        floatx4 a0 = floatx4{0.f,0.f,0.f,0.f}, a1 = a0;
#pragma unroll
        for (int kt = 0; kt < 4; ++kt) {
            bf16x8 b = ld8(&wbuf[cur][kt * 512 + lane * 8]);
            a0 = __builtin_amdgcn_mfma_f32_16x16x32_bf16(af[0][kt], b, a0, 0, 0, 0);
            a1 = __builtin_amdgcn_mfma_f32_16x16x32_bf16(af[1][kt], b, a1, 0, 0, 0);
        }
#pragma unroll
        for (int r = 0; r < 4; ++r) {
            sV[quad * 4 + r][nt * 16 + l15]      = f2bfn(fmaxf(a0[r] + bias, 0.f));
            sV[16 + quad * 4 + r][nt * 16 + l15] = f2bfn(fmaxf(a1[r] + bias, 0.f));
        }
        __syncthreads();
    }

    // ---- Phase 4: OUT = [H_OUT|V] @ dec_w^T + dec_b (weights in wbuf[0]) ----
    {
        floatx4 d0 = floatx4{0.f,0.f,0.f,0.f}, d1 = d0;
#pragma unroll
        for (int kt = 0; kt < 6; ++kt) {
            bf16x8 b = ld8(&wbuf[0][kt * 512 + lane * 8]);
            bf16x8 a0 = (kt < 4) ? af[0][kt] : ld8(&sV[l15][(kt - 4) * 32 + quad * 8]);
            bf16x8 a1 = (kt < 4) ? af[1][kt] : ld8(&sV[16 + l15][(kt - 4) * 32 + quad * 8]);
            d0 = __builtin_amdgcn_mfma_f32_16x16x32_bf16(a0, b, d0, 0, 0, 0);
            d1 = __builtin_amdgcn_mfma_f32_16x16x32_bf16(a1, b, d1, 0, 0, 0);
        }
        if (l15 < 10) {
            const float bias = dec_b[l15];
#pragma unroll
            for (int r = 0; r < 4; ++r) {
                sO[(quad * 4 + r) * 10 + l15]      = d0[r] + bias;
                sO[(16 + quad * 4 + r) * 10 + l15] = d1[r] + bias;
            }
        }
        // coalesced store: 320 consecutive f32 per wave
#pragma unroll
        for (int j = 0; j < 5; ++j) {
            int idx = j * 64 + lane;          // 0..319
            int row = idx / 10, col = idx % 10;
            int grow = wrow0 + row;
            if (grow < SIZE)
                out[(size_t)grow * 10 + col] = sO[row * 10 + col];
        }
    }
}

extern "C" void kernel_launch(void* const* d_in, const int* in_sizes, int n_in,
                              void* d_out, int out_size, void* d_ws, size_t ws_size,
                              hipStream_t stream) {
    const float* obs   = (const float*)d_in[0];
    const float* hid   = (const float*)d_in[1];
    const float* enc_w = (const float*)d_in[2];
    const float* enc_b = (const float*)d_in[3];
    const float* w_ih  = (const float*)d_in[4];
    const float* w_hh  = (const float*)d_in[5];
    const float* b_ih  = (const float*)d_in[6];
    const float* b_hh  = (const float*)d_in[7];
    // d_in[8..19]: dead code (bi-GRU / hard attention / q,k) — unused.
    const float* v_w   = (const float*)d_in[20];
    const float* v_b   = (const float*)d_in[21];
    const float* dec_w = (const float*)d_in[22];
    const float* dec_b = (const float*)d_in[23];
    unsigned short* wsw = (unsigned short*)d_ws;
    float* out = (float*)d_out;

    hipLaunchKernelGGL(cvt_weights, dim3((WS_TOTC + 255) / 256), dim3(256), 0, stream,
                       enc_w, w_ih, w_hh, v_w, dec_w, wsw);
    // 512 blocks x 4 waves x 32 rows = 65536 >= 65535; 3 blocks/CU resident
    hipLaunchKernelGGL(attn_critic_kernel, dim3(512), dim3(256), 0, stream,
                       obs, hid, enc_b, b_ih, b_hh, v_b, dec_b, wsw, out);
}

// Round 8
// 213.700 us; speedup vs baseline: 2.2033x; 1.0266x over previous
//
#include <hip/hip_runtime.h>
#include <stdint.h>

#define SIZE 65535

typedef __bf16 bf16x8 __attribute__((ext_vector_type(8)));
typedef float floatx4 __attribute__((ext_vector_type(4)));

// ws layout (bf16 elements), FRAGMENT-LINEAR: chunk = tile*64 + lane, 8 elems/chunk.
#define WS_ENCW 0        // [nt8][kt8][lane][8]        -> 32768
#define WS_WIH  32768    // [nt8][g3][kt4][lane][8]    -> 49152
#define WS_WHH  81920    // [nt8][g3][kt4][lane][8]    -> 49152
#define WS_VW   131072   // [nt4][kt4][lane][8]        -> 8192
#define WS_DECW 139264   // [kt6][lane][8] (rows>=10 zero) -> 3072
#define WS_TOTC 17792    // total chunks (x64x8 elems = 142336)

__device__ __forceinline__ unsigned short f2bf(float f) {
    union { float f; unsigned int u; } v; v.f = f;
    unsigned int u = v.u;
    return (unsigned short)((u + 0x7fffu + ((u >> 16) & 1u)) >> 16);
}
__device__ __forceinline__ float bf2f(unsigned short b) {
    union { unsigned int u; float f; } v; v.u = ((unsigned int)b) << 16;
    return v.f;
}
__device__ __forceinline__ float sigmf(float x) {
    x = fminf(fmaxf(x, -30.f), 30.f);
    return 1.f / (1.f + __expf(-x));
}
__device__ __forceinline__ float tanhfast(float x) {
    x = fminf(fmaxf(x, -15.f), 15.f);
    float e = __expf(2.f * x);
    return (e - 1.f) / (e + 1.f);
}

union BF8 { bf16x8 v; unsigned short s[8]; };

__device__ __forceinline__ bf16x8 cvt8g(const float* p) {
    float4 a = *reinterpret_cast<const float4*>(p);
    float4 b = *reinterpret_cast<const float4*>(p + 4);
    BF8 r;
    r.s[0] = f2bf(a.x); r.s[1] = f2bf(a.y); r.s[2] = f2bf(a.z); r.s[3] = f2bf(a.w);
    r.s[4] = f2bf(b.x); r.s[5] = f2bf(b.y); r.s[6] = f2bf(b.z); r.s[7] = f2bf(b.w);
    return r.v;
}
__device__ __forceinline__ bf16x8 ld8(const unsigned short* p) {
    return *reinterpret_cast<const bf16x8*>(p);
}

// async global->LDS, 16B per lane, no VGPR destination.
__device__ __forceinline__ void glds16(const unsigned short* g, unsigned short* l) {
    __builtin_amdgcn_global_load_lds(
        (const __attribute__((address_space(1))) unsigned int*)g,
        (__attribute__((address_space(3))) unsigned int*)l, 16, 0, 0);
}

// stage nfrags contiguous 1KB fragments; waves split the slots
__device__ __forceinline__ void stage_seq(unsigned short* dst, const unsigned short* src,
                                          int nfrags, int wave, int lane) {
    for (int s = wave; s < nfrags; s += 4)
        glds16(src + s * 512 + lane * 8, dst + s * 512);
}
// stage one GRU chunk ng = nt*3+g: slots 0..3 = w_ih kt0..3, slots 4..7 = w_hh kt0..3
__device__ __forceinline__ void stage_gru(unsigned short* dst, const unsigned short* wsw,
                                          int ng, int wave, int lane) {
    const int fo = (ng * 4 + wave) * 512 + lane * 8;
    glds16(wsw + WS_WIH + fo, dst + wave * 512);
    glds16(wsw + WS_WHH + fo, dst + (4 + wave) * 512);
}

// ---------- pre-kernel: f32 weights -> bf16 fragment-linear layout ----------
__global__ __launch_bounds__(256) void cvt_weights(
    const float* __restrict__ enc_w, const float* __restrict__ w_ih,
    const float* __restrict__ w_hh, const float* __restrict__ v_w,
    const float* __restrict__ dec_w, unsigned short* __restrict__ ws) {
    int c = blockIdx.x * 256 + threadIdx.x;
    if (c >= WS_TOTC) return;
    const int lane = c & 63;
    const int l = lane & 15;
    const int q = lane >> 4;
    const float* src; int row, col, stride; bool zero = false;
    if (c < 4096) {                      // enc_w [nt8][kt8]
        int lt = c >> 6; int nt = lt >> 3, kt = lt & 7;
        row = nt * 16 + l; col = kt * 32 + q * 8; src = enc_w; stride = 256;
    } else if (c < 10240) {              // w_ih [nt8][g3][kt4]
        int lt = (c - 4096) >> 6; int nt = lt / 12; int r2 = lt % 12;
        int g = r2 >> 2, kt = r2 & 3;
        row = g * 128 + nt * 16 + l; col = kt * 32 + q * 8; src = w_ih; stride = 128;
    } else if (c < 16384) {              // w_hh
        int lt = (c - 10240) >> 6; int nt = lt / 12; int r2 = lt % 12;
        int g = r2 >> 2, kt = r2 & 3;
        row = g * 128 + nt * 16 + l; col = kt * 32 + q * 8; src = w_hh; stride = 128;
    } else if (c < 17408) {              // v_w [nt4][kt4]
        int lt = (c - 16384) >> 6; int nt = lt >> 2, kt = lt & 3;
        row = nt * 16 + l; col = kt * 32 + q * 8; src = v_w; stride = 128;
    } else {                             // dec_w [kt6], zero-pad rows 10..15
        int kt = (c - 17408) >> 6;
        row = l; col = kt * 32 + q * 8; src = dec_w; stride = 192;
        zero = (l >= 10);
    }
    float4 a, b;
    if (zero) { a = make_float4(0.f,0.f,0.f,0.f); b = a; }
    else {
        const float* p = src + (size_t)row * stride + col;
        a = *reinterpret_cast<const float4*>(p);
        b = *reinterpret_cast<const float4*>(p + 4);
    }
    unsigned short* d = ws + (size_t)c * 8;
    d[0]=f2bf(a.x); d[1]=f2bf(a.y); d[2]=f2bf(a.z); d[3]=f2bf(a.w);
    d[4]=f2bf(b.x); d[5]=f2bf(b.y); d[6]=f2bf(b.z); d[7]=f2bf(b.w);
}

// ---------- main fused kernel (R2 skeleton + swapped-operand epilogues) ----------
// vs R2 (74us): phases 1-3 compute mfma(W_frag, data_frag) -> D[outcol][row].
// Same dot products, bit-identical values; but each thread now holds 4
// CONSECUTIVE outcols for one row, so:
//   - GRU hprev: 2 coalesced float4 loads/nt (was 8 scalar 32-line gathers)
//   - biases: one-time LDS stage (sBias) + float4 LDS reads (was 56 gathers)
//   - sA/sV activation writes: ushort4 (was scalar u16 x8)
// Sync structure, chunk schedule, staging, h_out end-store, f2bf, grid:
// byte-identical to R2. launch_bounds(256,2) (R7's (256,3) caused spill).
__global__ __launch_bounds__(256, 2) void attn_critic_kernel(
    const float* __restrict__ obs,    // [SIZE,256] f32
    const float* __restrict__ hid,    // [SIZE,128] f32
    const float* __restrict__ enc_b,  // [128] f32
    const float* __restrict__ b_ih,   // [384] f32
    const float* __restrict__ b_hh,   // [384] f32
    const float* __restrict__ v_b,    // [64] f32
    const float* __restrict__ dec_b,  // [10] f32
    const unsigned short* __restrict__ wsw,  // bf16 fragment-linear weights
    float* __restrict__ out)          // [SIZE*10] ++ [SIZE*128] f32
{
    // weight ring: 2 x 8KB (8 fragment slots each)
    __shared__ __align__(16) unsigned short wbuf[2][4096];
    __shared__ __align__(16) unsigned short sA[4][32][136];  // x then h_out
    __shared__ __align__(16) unsigned short sV[4][32][72];   // v
    __shared__ __align__(16) float sO[4][32][10];            // final logits
    // biases: [0..127]=enc_b [128..511]=b_ih [512..895]=b_hh [896..959]=v_b
    __shared__ __align__(16) float sBias[960];

    const int tid  = threadIdx.x;
    const int wave = tid >> 6;
    const int lane = tid & 63;
    const int l15  = lane & 15;
    const int quad = lane >> 4;
    const int wrow0 = (blockIdx.x * 4 + wave) * 32;

    int rA0 = wrow0 + l15;      rA0 = (rA0 < SIZE) ? rA0 : (SIZE - 1);
    int rA1 = wrow0 + 16 + l15; rA1 = (rA1 < SIZE) ? rA1 : (SIZE - 1);

    // ---- stage phase-1 chunk 0; latency hides under the prefetch below ----
    stage_seq(wbuf[0], wsw + WS_ENCW, 8, wave, lane);

    // ---- biases -> LDS (one-time; removes per-nt VMEM gathers) ----
    for (int i = tid; i < 960; i += 256) {
        float v;
        if (i < 128)      v = enc_b[i];
        else if (i < 512) v = b_ih[i - 128];
        else if (i < 896) v = b_hh[i - 512];
        else              v = v_b[i - 896];
        sBias[i] = v;
    }

    // ---- prefetch obs + hid fragments (B-operands now; same lane map) ----
    bf16x8 aob[2][8], hf[2][4];
    {
        const float* o0 = obs + (size_t)rA0 * 256;
        const float* o1 = obs + (size_t)rA1 * 256;
#pragma unroll
        for (int kt = 0; kt < 8; ++kt) {
            aob[0][kt] = cvt8g(o0 + kt * 32 + quad * 8);
            aob[1][kt] = cvt8g(o1 + kt * 32 + quad * 8);
        }
        const float* h0 = hid + (size_t)rA0 * 128;
        const float* h1 = hid + (size_t)rA1 * 128;
#pragma unroll
        for (int kt = 0; kt < 4; ++kt) {
            hf[0][kt] = cvt8g(h0 + kt * 32 + quad * 8);
            hf[1][kt] = cvt8g(h1 + kt * 32 + quad * 8);
        }
    }
    __builtin_amdgcn_sched_barrier(0);
    __syncthreads();   // chunk 0 staged + sBias written

    // ---- Phase 1: X = relu(OBS @ enc_w^T + enc_b), chunks 0..7 (SWAPPED) ----
#pragma unroll 1
    for (int nt = 0; nt < 8; ++nt) {
        const int cur = nt & 1;
        if (nt < 7) stage_seq(wbuf[cur ^ 1], wsw + WS_ENCW + (nt + 1) * 4096, 8, wave, lane);
        else        stage_gru(wbuf[cur ^ 1], wsw, 0, wave, lane);   // phase-2 chunk 0
        floatx4 d0 = floatx4{0.f,0.f,0.f,0.f}, d1 = d0;
#pragma unroll
        for (int kt = 0; kt < 8; ++kt) {
            bf16x8 b = ld8(&wbuf[cur][kt * 512 + lane * 8]);
            d0 = __builtin_amdgcn_mfma_f32_16x16x32_bf16(b, aob[0][kt], d0, 0, 0, 0);
            d1 = __builtin_amdgcn_mfma_f32_16x16x32_bf16(b, aob[1][kt], d1, 0, 0, 0);
        }
        const int oc0 = nt * 16 + quad * 4;
        const float4 ebv = *reinterpret_cast<const float4*>(&sBias[oc0]);
        const float eb[4] = {ebv.x, ebv.y, ebv.z, ebv.w};
        ushort4 p0, p1;
        p0.x = f2bf(fmaxf(d0[0] + eb[0], 0.f)); p0.y = f2bf(fmaxf(d0[1] + eb[1], 0.f));
        p0.z = f2bf(fmaxf(d0[2] + eb[2], 0.f)); p0.w = f2bf(fmaxf(d0[3] + eb[3], 0.f));
        p1.x = f2bf(fmaxf(d1[0] + eb[0], 0.f)); p1.y = f2bf(fmaxf(d1[1] + eb[1], 0.f));
        p1.z = f2bf(fmaxf(d1[2] + eb[2], 0.f)); p1.w = f2bf(fmaxf(d1[3] + eb[3], 0.f));
        *reinterpret_cast<ushort4*>(&sA[wave][l15][oc0])      = p0;
        *reinterpret_cast<ushort4*>(&sA[wave][16 + l15][oc0]) = p1;
        __syncthreads();   // staged chunk ready; all reads of wbuf[cur] done
    }

    bf16x8 xf[2][4];
#pragma unroll
    for (int kt = 0; kt < 4; ++kt) {
        xf[0][kt] = ld8(&sA[wave][l15][kt * 32 + quad * 8]);
        xf[1][kt] = ld8(&sA[wave][16 + l15][kt * 32 + quad * 8]);
    }

    // ---- Phase 2: GRU cell (SWAPPED; h_out bf16 -> sA), chunks ng=0..23 ----
#pragma unroll 1
    for (int nt = 0; nt < 8; ++nt) {
        const int oc0 = nt * 16 + quad * 4;
        // hprev: 2 coalesced float4 loads (rows = rA0/rA1, cols oc0..oc0+3)
        const float4 hp0v = *reinterpret_cast<const float4*>(hid + (size_t)rA0 * 128 + oc0);
        const float4 hp1v = *reinterpret_cast<const float4*>(hid + (size_t)rA1 * 128 + oc0);
        floatx4 gi[3][2], gh[3][2];
#pragma unroll
        for (int g = 0; g < 3; ++g) {
            gi[g][0] = floatx4{0.f,0.f,0.f,0.f}; gi[g][1] = gi[g][0];
            gh[g][0] = gi[g][0]; gh[g][1] = gi[g][0];
        }
#pragma unroll
        for (int g = 0; g < 3; ++g) {
            const int cur = (nt + g) & 1;
            const int ng = nt * 3 + g + 1;
            if (ng < 24) stage_gru(wbuf[cur ^ 1], wsw, ng, wave, lane);
            else         stage_seq(wbuf[cur ^ 1], wsw + WS_VW, 4, wave, lane); // phase-3 chunk 0
#pragma unroll
            for (int kt = 0; kt < 4; ++kt) {
                bf16x8 bi = ld8(&wbuf[cur][kt * 512 + lane * 8]);
                bf16x8 bh = ld8(&wbuf[cur][(4 + kt) * 512 + lane * 8]);
                gi[g][0] = __builtin_amdgcn_mfma_f32_16x16x32_bf16(bi, xf[0][kt], gi[g][0], 0, 0, 0);
                gi[g][1] = __builtin_amdgcn_mfma_f32_16x16x32_bf16(bi, xf[1][kt], gi[g][1], 0, 0, 0);
                gh[g][0] = __builtin_amdgcn_mfma_f32_16x16x32_bf16(bh, hf[0][kt], gh[g][0], 0, 0, 0);
                gh[g][1] = __builtin_amdgcn_mfma_f32_16x16x32_bf16(bh, hf[1][kt], gh[g][1], 0, 0, 0);
            }
            __syncthreads();
        }
        // biases (float4 LDS reads)
        const float4 birv = *reinterpret_cast<const float4*>(&sBias[128 + oc0]);
        const float4 bizv = *reinterpret_cast<const float4*>(&sBias[256 + oc0]);
        const float4 binv = *reinterpret_cast<const float4*>(&sBias[384 + oc0]);
        const float4 bhrv = *reinterpret_cast<const float4*>(&sBias[512 + oc0]);
        const float4 bhzv = *reinterpret_cast<const float4*>(&sBias[640 + oc0]);
        const float4 bhnv = *reinterpret_cast<const float4*>(&sBias[768 + oc0]);
        const float bir[4] = {birv.x, birv.y, birv.z, birv.w};
        const float biz[4] = {bizv.x, bizv.y, bizv.z, bizv.w};
        const float bin[4] = {binv.x, binv.y, binv.z, binv.w};
        const float bhr[4] = {bhrv.x, bhrv.y, bhrv.z, bhrv.w};
        const float bhz[4] = {bhzv.x, bhzv.y, bhzv.z, bhzv.w};
        const float bhn[4] = {bhnv.x, bhnv.y, bhnv.z, bhnv.w};
        const float hp0[4] = {hp0v.x, hp0v.y, hp0v.z, hp0v.w};
        const float hp1[4] = {hp1v.x, hp1v.y, hp1v.z, hp1v.w};
        ushort4 h0p, h1p;
        {
            float ho[4];
#pragma unroll
            for (int r = 0; r < 4; ++r) {
                float rg = sigmf(gi[0][0][r] + bir[r] + gh[0][0][r] + bhr[r]);
                float zg = sigmf(gi[1][0][r] + biz[r] + gh[1][0][r] + bhz[r]);
                float ng2 = tanhfast(gi[2][0][r] + bin[r] + rg * (gh[2][0][r] + bhn[r]));
                ho[r] = (1.f - zg) * ng2 + zg * hp0[r];
            }
            h0p.x = f2bf(ho[0]); h0p.y = f2bf(ho[1]); h0p.z = f2bf(ho[2]); h0p.w = f2bf(ho[3]);
        }
        {
            float ho[4];
#pragma unroll
            for (int r = 0; r < 4; ++r) {
                float rg = sigmf(gi[0][1][r] + bir[r] + gh[0][1][r] + bhr[r]);
                float zg = sigmf(gi[1][1][r] + biz[r] + gh[1][1][r] + bhz[r]);
                float ng2 = tanhfast(gi[2][1][r] + bin[r] + rg * (gh[2][1][r] + bhn[r]));
                ho[r] = (1.f - zg) * ng2 + zg * hp1[r];
            }
            h1p.x = f2bf(ho[0]); h1p.y = f2bf(ho[1]); h1p.z = f2bf(ho[2]); h1p.w = f2bf(ho[3]);
        }
        *reinterpret_cast<ushort4*>(&sA[wave][l15][oc0])      = h0p;
        *reinterpret_cast<ushort4*>(&sA[wave][16 + l15][oc0]) = h1p;
    }

    // ---- Phase 3: V = relu(H_OUT @ v_w^T + v_b) -> sV (SWAPPED) ----
    bf16x8 af[2][4];
#pragma unroll
    for (int kt = 0; kt < 4; ++kt) {
        af[0][kt] = ld8(&sA[wave][l15][kt * 32 + quad * 8]);
        af[1][kt] = ld8(&sA[wave][16 + l15][kt * 32 + quad * 8]);
    }
#pragma unroll 1
    for (int nt = 0; nt < 4; ++nt) {
        const int cur = nt & 1;
        if (nt < 3) stage_seq(wbuf[cur ^ 1], wsw + WS_VW + (nt + 1) * 2048, 4, wave, lane);
        else        stage_seq(wbuf[cur ^ 1], wsw + WS_DECW, 6, wave, lane);  // phase-4 chunk
        floatx4 a0 = floatx4{0.f,0.f,0.f,0.f}, a1 = a0;
#pragma unroll
        for (int kt = 0; kt < 4; ++kt) {
            bf16x8 b = ld8(&wbuf[cur][kt * 512 + lane * 8]);
            a0 = __builtin_amdgcn_mfma_f32_16x16x32_bf16(b, af[0][kt], a0, 0, 0, 0);
            a1 = __builtin_amdgcn_mfma_f32_16x16x32_bf16(b, af[1][kt], a1, 0, 0, 0);
        }
        const int vc0 = nt * 16 + quad * 4;
        const float4 vbv = *reinterpret_cast<const float4*>(&sBias[896 + vc0]);
        const float vb[4] = {vbv.x, vbv.y, vbv.z, vbv.w};
        ushort4 q0, q1;
        q0.x = f2bf(fmaxf(a0[0] + vb[0], 0.f)); q0.y = f2bf(fmaxf(a0[1] + vb[1], 0.f));
        q0.z = f2bf(fmaxf(a0[2] + vb[2], 0.f)); q0.w = f2bf(fmaxf(a0[3] + vb[3], 0.f));
        q1.x = f2bf(fmaxf(a1[0] + vb[0], 0.f)); q1.y = f2bf(fmaxf(a1[1] + vb[1], 0.f));
        q1.z = f2bf(fmaxf(a1[2] + vb[2], 0.f)); q1.w = f2bf(fmaxf(a1[3] + vb[3], 0.f));
        *reinterpret_cast<ushort4*>(&sV[wave][l15][vc0])      = q0;
        *reinterpret_cast<ushort4*>(&sV[wave][16 + l15][vc0]) = q1;
        __syncthreads();
    }

    // ---- Phase 4: OUT = [H_OUT|V] @ dec_w^T + dec_b (UNswapped; wbuf[0]) ----
    {
        floatx4 d0 = floatx4{0.f,0.f,0.f,0.f}, d1 = d0;
#pragma unroll
        for (int kt = 0; kt < 6; ++kt) {
            bf16x8 b = ld8(&wbuf[0][kt * 512 + lane * 8]);
            bf16x8 a0 = (kt < 4) ? af[0][kt] : ld8(&sV[wave][l15][(kt - 4) * 32 + quad * 8]);
            bf16x8 a1 = (kt < 4) ? af[1][kt] : ld8(&sV[wave][16 + l15][(kt - 4) * 32 + quad * 8]);
            d0 = __builtin_amdgcn_mfma_f32_16x16x32_bf16(a0, b, d0, 0, 0, 0);
            d1 = __builtin_amdgcn_mfma_f32_16x16x32_bf16(a1, b, d1, 0, 0, 0);
        }
        if (l15 < 10) {
            const float bias = dec_b[l15];
#pragma unroll
            for (int r = 0; r < 4; ++r) {
                sO[wave][quad * 4 + r][l15]      = d0[r] + bias;
                sO[wave][16 + quad * 4 + r][l15] = d1[r] + bias;
            }
        }
        // coalesced store: 320 consecutive f32 per wave
#pragma unroll
        for (int j = 0; j < 5; ++j) {
            int idx = j * 64 + lane;          // 0..319
            int row = idx / 10, col = idx % 10;
            int grow = wrow0 + row;
            if (grow < SIZE)
                out[(size_t)grow * 10 + col] = sO[wave][row][col];
        }
    }

    // ---- h_out -> global, coalesced full lines (from sA, as R2) ----
    {
        float* out_h = out + (size_t)SIZE * 10;
#pragma unroll 1
        for (int it = 0; it < 16; ++it) {
            int idx = it * 256 + lane * 4;   // over [32][128]
            int rr = idx >> 7, cc = idx & 127;
            int grow = wrow0 + rr;
            if (grow < SIZE) {
                float2 p0 = make_float2(bf2f(sA[wave][rr][cc]),     bf2f(sA[wave][rr][cc + 1]));
                float2 p1 = make_float2(bf2f(sA[wave][rr][cc + 2]), bf2f(sA[wave][rr][cc + 3]));
                float* dst = out_h + (size_t)grow * 128 + cc;
                *reinterpret_cast<float2*>(dst)     = p0;
                *reinterpret_cast<float2*>(dst + 2) = p1;
            }
        }
    }
}

extern "C" void kernel_launch(void* const* d_in, const int* in_sizes, int n_in,
                              void* d_out, int out_size, void* d_ws, size_t ws_size,
                              hipStream_t stream) {
    const float* obs   = (const float*)d_in[0];
    const float* hid   = (const float*)d_in[1];
    const float* enc_w = (const float*)d_in[2];
    const float* enc_b = (const float*)d_in[3];
    const float* w_ih  = (const float*)d_in[4];
    const float* w_hh  = (const float*)d_in[5];
    const float* b_ih  = (const float*)d_in[6];
    const float* b_hh  = (const float*)d_in[7];
    // d_in[8..19]: dead code (bi-GRU / hard attention / q,k) — unused.
    const float* v_w   = (const float*)d_in[20];
    const float* v_b   = (const float*)d_in[21];
    const float* dec_w = (const float*)d_in[22];
    const float* dec_b = (const float*)d_in[23];
    unsigned short* wsw = (unsigned short*)d_ws;
    float* out = (float*)d_out;

    hipLaunchKernelGGL(cvt_weights, dim3((WS_TOTC + 255) / 256), dim3(256), 0, stream,
                       enc_w, w_ih, w_hh, v_w, dec_w, wsw);
    // 512 blocks x 4 waves x 32 rows = 65536 >= 65535; 2 blocks/CU resident
    hipLaunchKernelGGL(attn_critic_kernel, dim3(512), dim3(256), 0, stream,
                       obs, hid, enc_b, b_ih, b_hh, v_b, dec_b, wsw, out);
}

// Round 9
// 211.357 us; speedup vs baseline: 2.2277x; 1.0111x over previous
//
#include <hip/hip_runtime.h>
#include <stdint.h>

#define SIZE 65535

typedef __bf16 bf16x8 __attribute__((ext_vector_type(8)));
typedef float floatx4 __attribute__((ext_vector_type(4)));

// ws layout (bf16 elements), FRAGMENT-LINEAR: chunk = tile*64 + lane, 8 elems/chunk.
#define WS_ENCW 0        // [nt8][kt8][lane][8]        -> 32768
#define WS_WIH  32768    // [nt8][g3][kt4][lane][8]    -> 49152
#define WS_WHH  81920    // [nt8][g3][kt4][lane][8]    -> 49152
#define WS_VW   131072   // [nt4][kt4][lane][8]        -> 8192
#define WS_DECW 139264   // [kt6][lane][8] (rows>=10 zero) -> 3072
#define WS_TOTC 17792    // total chunks (x64x8 elems = 142336)

__device__ __forceinline__ unsigned short f2bf(float f) {
    union { float f; unsigned int u; } v; v.f = f;
    unsigned int u = v.u;
    return (unsigned short)((u + 0x7fffu + ((u >> 16) & 1u)) >> 16);
}
__device__ __forceinline__ float bf2f(unsigned short b) {
    union { unsigned int u; float f; } v; v.u = ((unsigned int)b) << 16;
    return v.f;
}
__device__ __forceinline__ float sigmf(float x) {
    x = fminf(fmaxf(x, -30.f), 30.f);
    return 1.f / (1.f + __expf(-x));
}
__device__ __forceinline__ float tanhfast(float x) {
    x = fminf(fmaxf(x, -15.f), 15.f);
    float e = __expf(2.f * x);
    return (e - 1.f) / (e + 1.f);
}

union BF8 { bf16x8 v; unsigned short s[8]; };

__device__ __forceinline__ bf16x8 cvt8g(const float* p) {
    float4 a = *reinterpret_cast<const float4*>(p);
    float4 b = *reinterpret_cast<const float4*>(p + 4);
    BF8 r;
    r.s[0] = f2bf(a.x); r.s[1] = f2bf(a.y); r.s[2] = f2bf(a.z); r.s[3] = f2bf(a.w);
    r.s[4] = f2bf(b.x); r.s[5] = f2bf(b.y); r.s[6] = f2bf(b.z); r.s[7] = f2bf(b.w);
    return r.v;
}
__device__ __forceinline__ bf16x8 ld8(const unsigned short* p) {
    return *reinterpret_cast<const bf16x8*>(p);
}

// async global->LDS, 16B per lane, no VGPR destination.
__device__ __forceinline__ void glds16(const unsigned short* g, unsigned short* l) {
    __builtin_amdgcn_global_load_lds(
        (const __attribute__((address_space(1))) unsigned int*)g,
        (__attribute__((address_space(3))) unsigned int*)l, 16, 0, 0);
}

// stage nfrags contiguous 1KB fragments; waves split the slots
__device__ __forceinline__ void stage_seq(unsigned short* dst, const unsigned short* src,
                                          int nfrags, int wave, int lane) {
    for (int s = wave; s < nfrags; s += 4)
        glds16(src + s * 512 + lane * 8, dst + s * 512);
}
// stage one GRU chunk ng = nt*3+g: slots 0..3 = w_ih kt0..3, slots 4..7 = w_hh kt0..3
__device__ __forceinline__ void stage_gru(unsigned short* dst, const unsigned short* wsw,
                                          int ng, int wave, int lane) {
    const int fo = (ng * 4 + wave) * 512 + lane * 8;
    glds16(wsw + WS_WIH + fo, dst + wave * 512);
    glds16(wsw + WS_WHH + fo, dst + (4 + wave) * 512);
}
// stage TWO GRU chunks (16KB): ng0 -> bytes 0..8KB, ng0+1 -> 8..16KB
__device__ __forceinline__ void stage_gru2(unsigned short* dst, const unsigned short* wsw,
                                           int ng0, int wave, int lane) {
    stage_gru(dst, wsw, ng0, wave, lane);
    stage_gru(dst + 4096, wsw, ng0 + 1, wave, lane);
}

// ---------- pre-kernel: f32 weights -> bf16 fragment-linear layout ----------
__global__ __launch_bounds__(256) void cvt_weights(
    const float* __restrict__ enc_w, const float* __restrict__ w_ih,
    const float* __restrict__ w_hh, const float* __restrict__ v_w,
    const float* __restrict__ dec_w, unsigned short* __restrict__ ws) {
    int c = blockIdx.x * 256 + threadIdx.x;
    if (c >= WS_TOTC) return;
    const int lane = c & 63;
    const int l = lane & 15;
    const int q = lane >> 4;
    const float* src; int row, col, stride; bool zero = false;
    if (c < 4096) {                      // enc_w [nt8][kt8]
        int lt = c >> 6; int nt = lt >> 3, kt = lt & 7;
        row = nt * 16 + l; col = kt * 32 + q * 8; src = enc_w; stride = 256;
    } else if (c < 10240) {              // w_ih [nt8][g3][kt4]
        int lt = (c - 4096) >> 6; int nt = lt / 12; int r2 = lt % 12;
        int g = r2 >> 2, kt = r2 & 3;
        row = g * 128 + nt * 16 + l; col = kt * 32 + q * 8; src = w_ih; stride = 128;
    } else if (c < 16384) {              // w_hh
        int lt = (c - 10240) >> 6; int nt = lt / 12; int r2 = lt % 12;
        int g = r2 >> 2, kt = r2 & 3;
        row = g * 128 + nt * 16 + l; col = kt * 32 + q * 8; src = w_hh; stride = 128;
    } else if (c < 17408) {              // v_w [nt4][kt4]
        int lt = (c - 16384) >> 6; int nt = lt >> 2, kt = lt & 3;
        row = nt * 16 + l; col = kt * 32 + q * 8; src = v_w; stride = 128;
    } else {                             // dec_w [kt6], zero-pad rows 10..15
        int kt = (c - 17408) >> 6;
        row = l; col = kt * 32 + q * 8; src = dec_w; stride = 192;
        zero = (l >= 10);
    }
    float4 a, b;
    if (zero) { a = make_float4(0.f,0.f,0.f,0.f); b = a; }
    else {
        const float* p = src + (size_t)row * stride + col;
        a = *reinterpret_cast<const float4*>(p);
        b = *reinterpret_cast<const float4*>(p + 4);
    }
    unsigned short* d = ws + (size_t)c * 8;
    d[0]=f2bf(a.x); d[1]=f2bf(a.y); d[2]=f2bf(a.z); d[3]=f2bf(a.w);
    d[4]=f2bf(b.x); d[5]=f2bf(b.y); d[6]=f2bf(b.z); d[7]=f2bf(b.w);
}

// one GRU ng-chunk's MFMA block: wb = 8KB sub-slot, g compile-time
#define DO_NG(WB, G, GI, GH)                                                               \
    {                                                                                      \
        _Pragma("unroll")                                                                  \
        for (int kt = 0; kt < 4; ++kt) {                                                   \
            bf16x8 bi = ld8((WB) + kt * 512 + lane * 8);                                   \
            bf16x8 bh = ld8((WB) + (4 + kt) * 512 + lane * 8);                             \
            GI[G][0] = __builtin_amdgcn_mfma_f32_16x16x32_bf16(xf[0][kt], bi, GI[G][0], 0, 0, 0); \
            GI[G][1] = __builtin_amdgcn_mfma_f32_16x16x32_bf16(xf[1][kt], bi, GI[G][1], 0, 0, 0); \
            GH[G][0] = __builtin_amdgcn_mfma_f32_16x16x32_bf16(hf[0][kt], bh, GH[G][0], 0, 0, 0); \
            GH[G][1] = __builtin_amdgcn_mfma_f32_16x16x32_bf16(hf[1][kt], bh, GH[G][1], 0, 0, 0); \
        }                                                                                  \
    }

// ---------- main fused kernel: R2 skeleton, 16KB steps (18 barriers vs 37) ----------
// Experiment: R2 verbatim math/staging/epilogues, but 2 weight-chunks staged &
// computed per barrier step. Discriminates "fixed cost per barrier-step"
// (~4800cyc/step law -> time halves) vs "per-byte" (time unchanged).
// LDS: wbuf 2x16KB + sA/sV/sO overlay pool (h_out stored before phase 3)
// = 66KB -> 2 blocks/CU. launch_bounds(256,2): VGPR cap 256 (phase2 holds two
// nt accumulator sets ~190 VGPR, no spill at 2 waves/SIMD).
__global__ __launch_bounds__(256, 2) void attn_critic_kernel(
    const float* __restrict__ obs,    // [SIZE,256] f32
    const float* __restrict__ hid,    // [SIZE,128] f32
    const float* __restrict__ enc_b,  // [128] f32
    const float* __restrict__ b_ih,   // [384] f32
    const float* __restrict__ b_hh,   // [384] f32
    const float* __restrict__ v_b,    // [64] f32
    const float* __restrict__ dec_b,  // [10] f32
    const unsigned short* __restrict__ wsw,  // bf16 fragment-linear weights
    float* __restrict__ out)          // [SIZE*10] ++ [SIZE*128] f32
{
    // weight ring: 2 x 16KB (16 fragment slots each)
    __shared__ __align__(16) unsigned short wbuf[2][8192];
    // per-wave pool: sA [32][136]; sV/sO overlay after h_out stored
    __shared__ __align__(16) unsigned short pool[4][4352];

    const int tid  = threadIdx.x;
    const int wave = tid >> 6;
    const int lane = tid & 63;
    const int l15  = lane & 15;
    const int quad = lane >> 4;
    const int wrow0 = (blockIdx.x * 4 + wave) * 32;

    unsigned short (*sA)[136] = (unsigned short(*)[136])&pool[wave][0];  // [32][136]
    unsigned short (*sV)[72]  = (unsigned short(*)[72]) &pool[wave][0];  // [32][72] overlay
    float* sO = (float*)&pool[wave][2304];                               // [32][10] overlay

    int rA0 = wrow0 + l15;      rA0 = (rA0 < SIZE) ? rA0 : (SIZE - 1);
    int rA1 = wrow0 + 16 + l15; rA1 = (rA1 < SIZE) ? rA1 : (SIZE - 1);

    // ---- stage phase-1 step 0 (16KB = enc nt0,nt1); hides under prefetch ----
    stage_seq(wbuf[0], wsw + WS_ENCW, 16, wave, lane);

    // ---- prefetch obs + hid A-fragments ----
    bf16x8 aob[2][8], hf[2][4];
    {
        const float* o0 = obs + (size_t)rA0 * 256;
        const float* o1 = obs + (size_t)rA1 * 256;
#pragma unroll
        for (int kt = 0; kt < 8; ++kt) {
            aob[0][kt] = cvt8g(o0 + kt * 32 + quad * 8);
            aob[1][kt] = cvt8g(o1 + kt * 32 + quad * 8);
        }
        const float* h0 = hid + (size_t)rA0 * 128;
        const float* h1 = hid + (size_t)rA1 * 128;
#pragma unroll
        for (int kt = 0; kt < 4; ++kt) {
            hf[0][kt] = cvt8g(h0 + kt * 32 + quad * 8);
            hf[1][kt] = cvt8g(h1 + kt * 32 + quad * 8);
        }
    }
    __builtin_amdgcn_sched_barrier(0);
    __syncthreads();   // step 0 staged

    // ---- Phase 1: X = relu(OBS @ enc_w^T + enc_b), 4 steps x 2 nt ----
#pragma unroll 1
    for (int step = 0; step < 4; ++step) {
        const int cur = step & 1;
        if (step < 3) stage_seq(wbuf[cur ^ 1], wsw + WS_ENCW + (step + 1) * 8192, 16, wave, lane);
        else          stage_gru2(wbuf[cur ^ 1], wsw, 0, wave, lane);   // phase-2 ng 0,1
#pragma unroll
        for (int h = 0; h < 2; ++h) {
            const int nt = step * 2 + h;
            const unsigned short* wb = &wbuf[cur][h * 4096];
            const float bias = enc_b[nt * 16 + l15];
            floatx4 a0 = floatx4{0.f,0.f,0.f,0.f}, a1 = a0;
#pragma unroll
            for (int kt = 0; kt < 8; ++kt) {
                bf16x8 b = ld8(wb + kt * 512 + lane * 8);
                a0 = __builtin_amdgcn_mfma_f32_16x16x32_bf16(aob[0][kt], b, a0, 0, 0, 0);
                a1 = __builtin_amdgcn_mfma_f32_16x16x32_bf16(aob[1][kt], b, a1, 0, 0, 0);
            }
#pragma unroll
            for (int r = 0; r < 4; ++r) {
                sA[quad * 4 + r][nt * 16 + l15]      = f2bf(fmaxf(a0[r] + bias, 0.f));
                sA[16 + quad * 4 + r][nt * 16 + l15] = f2bf(fmaxf(a1[r] + bias, 0.f));
            }
        }
        __syncthreads();
    }

    bf16x8 xf[2][4];
#pragma unroll
    for (int kt = 0; kt < 4; ++kt) {
        xf[0][kt] = ld8(&sA[l15][kt * 32 + quad * 8]);
        xf[1][kt] = ld8(&sA[16 + l15][kt * 32 + quad * 8]);
    }

    // ---- Phase 2: GRU cell, 12 steps x 2 ng; u-groups of 3 steps = 2 nt ----
    // step s reads wbuf[s&1]; s stages pair for s+1. Entry: phase1 staged ng0,1
    // into wbuf[0] and phase2 step0 parity is 0.  g indices compile-time per u.
#pragma unroll 1
    for (int u = 0; u < 4; ++u) {
        const int nt0 = u * 2, nt1 = nt0 + 1;
        const int nr0 = nt0 * 16 + l15, nr1 = nt1 * 16 + l15;
        // hprev + biases for both nt (R2-style scalar loads, L2-hot)
        float hp0[2][4], hp1[2][4];
#pragma unroll
        for (int m = 0; m < 2; ++m)
#pragma unroll
            for (int r = 0; r < 4; ++r) {
                const int grow = wrow0 + m * 16 + quad * 4 + r;
                const int rowc = (grow < SIZE) ? grow : (SIZE - 1);
                hp0[m][r] = hid[(size_t)rowc * 128 + nr0];
                hp1[m][r] = hid[(size_t)rowc * 128 + nr1];
            }
        const float bir0 = b_ih[nr0], biz0 = b_ih[nr0 + 128], bin0 = b_ih[nr0 + 256];
        const float bhr0 = b_hh[nr0], bhz0 = b_hh[nr0 + 128], bhn0 = b_hh[nr0 + 256];
        const float bir1 = b_ih[nr1], biz1 = b_ih[nr1 + 128], bin1 = b_ih[nr1 + 256];
        const float bhr1 = b_hh[nr1], bhz1 = b_hh[nr1 + 128], bhn1 = b_hh[nr1 + 256];

        floatx4 gi0[3][2], gh0[3][2], gi1[3][2], gh1[3][2];
#pragma unroll
        for (int g = 0; g < 3; ++g) {
            gi0[g][0] = floatx4{0.f,0.f,0.f,0.f}; gi0[g][1] = gi0[g][0];
            gh0[g][0] = gi0[g][0]; gh0[g][1] = gi0[g][0];
            gi1[g][0] = gi0[g][0]; gi1[g][1] = gi0[g][0];
            gh1[g][0] = gi0[g][0]; gh1[g][1] = gi0[g][0];
        }
        // ---- step 3u: (nt0,g0) (nt0,g1) ----
        {
            const int cur = u & 1;                      // (3u)&1 == u&1
            stage_gru2(wbuf[cur ^ 1], wsw, 6 * u + 2, wave, lane);
            DO_NG(&wbuf[cur][0],    0, gi0, gh0);
            DO_NG(&wbuf[cur][4096], 1, gi0, gh0);
            __syncthreads();
        }
        // ---- step 3u+1: (nt0,g2) (nt1,g0) ----
        {
            const int cur = (u + 1) & 1;
            stage_gru2(wbuf[cur ^ 1], wsw, 6 * u + 4, wave, lane);
            DO_NG(&wbuf[cur][0],    2, gi0, gh0);
            DO_NG(&wbuf[cur][4096], 0, gi1, gh1);
            __syncthreads();
            // nt0 complete -> epilogue (regs + own-wave LDS writes)
#pragma unroll
            for (int m = 0; m < 2; ++m)
#pragma unroll
                for (int r = 0; r < 4; ++r) {
                    float rg = sigmf(gi0[0][m][r] + bir0 + gh0[0][m][r] + bhr0);
                    float zg = sigmf(gi0[1][m][r] + biz0 + gh0[1][m][r] + bhz0);
                    float ng2 = tanhfast(gi0[2][m][r] + bin0 + rg * (gh0[2][m][r] + bhn0));
                    float ho = (1.f - zg) * ng2 + zg * hp0[m][r];
                    sA[m * 16 + quad * 4 + r][nr0] = f2bf(ho);
                }
        }
        // ---- step 3u+2: (nt1,g1) (nt1,g2) ----
        {
            const int cur = u & 1;                      // (3u+2)&1 == u&1
            if (u < 3) stage_gru2(wbuf[cur ^ 1], wsw, 6 * u + 6, wave, lane);
            else       stage_seq(wbuf[cur ^ 1], wsw + WS_VW, 16, wave, lane);  // all v_w
            DO_NG(&wbuf[cur][0],    1, gi1, gh1);
            DO_NG(&wbuf[cur][4096], 2, gi1, gh1);
            __syncthreads();
#pragma unroll
            for (int m = 0; m < 2; ++m)
#pragma unroll
                for (int r = 0; r < 4; ++r) {
                    float rg = sigmf(gi1[0][m][r] + bir1 + gh1[0][m][r] + bhr1);
                    float zg = sigmf(gi1[1][m][r] + biz1 + gh1[1][m][r] + bhz1);
                    float ng2 = tanhfast(gi1[2][m][r] + bin1 + rg * (gh1[2][m][r] + bhn1));
                    float ho = (1.f - zg) * ng2 + zg * hp1[m][r];
                    sA[m * 16 + quad * 4 + r][nr1] = f2bf(ho);
                }
        }
    }
    // parity after 12 phase-2 steps: v_w sits in wbuf[0]

    // ---- capture h_out fragments, store h_out (sA dies; sV/sO overlay) ----
    bf16x8 af[2][4];
#pragma unroll
    for (int kt = 0; kt < 4; ++kt) {
        af[0][kt] = ld8(&sA[l15][kt * 32 + quad * 8]);
        af[1][kt] = ld8(&sA[16 + l15][kt * 32 + quad * 8]);
    }
    {
        float* out_h = out + (size_t)SIZE * 10;
#pragma unroll 1
        for (int it = 0; it < 16; ++it) {
            int idx = it * 256 + lane * 4;   // over [32][128]
            int rr = idx >> 7, cc = idx & 127;
            int grow = wrow0 + rr;
            if (grow < SIZE) {
                float2 p0 = make_float2(bf2f(sA[rr][cc]),     bf2f(sA[rr][cc + 1]));
                float2 p1 = make_float2(bf2f(sA[rr][cc + 2]), bf2f(sA[rr][cc + 3]));
                float* dst = out_h + (size_t)grow * 128 + cc;
                *reinterpret_cast<float2*>(dst)     = p0;
                *reinterpret_cast<float2*>(dst + 2) = p1;
            }
        }
    }

    // ---- Phase 3: V = relu(H_OUT @ v_w^T + v_b), single step (v_w in wbuf[0]) ----
    stage_seq(wbuf[1], wsw + WS_DECW, 6, wave, lane);   // dec for phase 4
#pragma unroll 1
    for (int nt = 0; nt < 4; ++nt) {
        const float bias = v_b[nt * 16 + l15];
        floatx4 a0 = floatx4{0.f,0.f,0.f,0.f}, a1 = a0;
#pragma unroll
        for (int kt = 0; kt < 4; ++kt) {
            bf16x8 b = ld8(&wbuf[0][(nt * 4 + kt) * 512 + lane * 8]);
            a0 = __builtin_amdgcn_mfma_f32_16x16x32_bf16(af[0][kt], b, a0, 0, 0, 0);
            a1 = __builtin_amdgcn_mfma_f32_16x16x32_bf16(af[1][kt], b, a1, 0, 0, 0);
        }
#pragma unroll
        for (int r = 0; r < 4; ++r) {
            sV[quad * 4 + r][nt * 16 + l15]      = f2bf(fmaxf(a0[r] + bias, 0.f));
            sV[16 + quad * 4 + r][nt * 16 + l15] = f2bf(fmaxf(a1[r] + bias, 0.f));
        }
    }
    __syncthreads();   // dec staged (sV is per-wave; barrier only for wbuf[1])

    // ---- Phase 4: OUT = [H_OUT|V] @ dec_w^T + dec_b (weights in wbuf[1]) ----
    {
        floatx4 d0 = floatx4{0.f,0.f,0.f,0.f}, d1 = d0;
#pragma unroll
        for (int kt = 0; kt < 6; ++kt) {
            bf16x8 b = ld8(&wbuf[1][kt * 512 + lane * 8]);
            bf16x8 a0 = (kt < 4) ? af[0][kt] : ld8(&sV[l15][(kt - 4) * 32 + quad * 8]);
            bf16x8 a1 = (kt < 4) ? af[1][kt] : ld8(&sV[16 + l15][(kt - 4) * 32 + quad * 8]);
            d0 = __builtin_amdgcn_mfma_f32_16x16x32_bf16(a0, b, d0, 0, 0, 0);
            d1 = __builtin_amdgcn_mfma_f32_16x16x32_bf16(a1, b, d1, 0, 0, 0);
        }
        if (l15 < 10) {
            const float bias = dec_b[l15];
#pragma unroll
            for (int r = 0; r < 4; ++r) {
                sO[(quad * 4 + r) * 10 + l15]      = d0[r] + bias;
                sO[(16 + quad * 4 + r) * 10 + l15] = d1[r] + bias;
            }
        }
        // coalesced store: 320 consecutive f32 per wave
#pragma unroll
        for (int j = 0; j < 5; ++j) {
            int idx = j * 64 + lane;          // 0..319
            int row = idx / 10, col = idx % 10;
            int grow = wrow0 + row;
            if (grow < SIZE)
                out[(size_t)grow * 10 + col] = sO[row * 10 + col];
        }
    }
}

extern "C" void kernel_launch(void* const* d_in, const int* in_sizes, int n_in,
                              void* d_out, int out_size, void* d_ws, size_t ws_size,
                              hipStream_t stream) {
    const float* obs   = (const float*)d_in[0];
    const float* hid   = (const float*)d_in[1];
    const float* enc_w = (const float*)d_in[2];
    const float* enc_b = (const float*)d_in[3];
    const float* w_ih  = (const float*)d_in[4];
    const float* w_hh  = (const float*)d_in[5];
    const float* b_ih  = (const float*)d_in[6];
    const float* b_hh  = (const float*)d_in[7];
    // d_in[8..19]: dead code (bi-GRU / hard attention / q,k) — unused.
    const float* v_w   = (const float*)d_in[20];
    const float* v_b   = (const float*)d_in[21];
    const float* dec_w = (const float*)d_in[22];
    const float* dec_b = (const float*)d_in[23];
    unsigned short* wsw = (unsigned short*)d_ws;
    float* out = (float*)d_out;

    hipLaunchKernelGGL(cvt_weights, dim3((WS_TOTC + 255) / 256), dim3(256), 0, stream,
                       enc_w, w_ih, w_hh, v_w, dec_w, wsw);
    // 512 blocks x 4 waves x 32 rows = 65536 >= 65535; 2 blocks/CU resident
    hipLaunchKernelGGL(attn_critic_kernel, dim3(512), dim3(256), 0, stream,
                       obs, hid, enc_b, b_ih, b_hh, v_b, dec_b, wsw, out);
}

// Round 10
// 208.472 us; speedup vs baseline: 2.2585x; 1.0138x over previous
//
#include <hip/hip_runtime.h>
#include <stdint.h>

#define SIZE 65535

typedef __bf16 bf16x8 __attribute__((ext_vector_type(8)));
typedef float floatx4 __attribute__((ext_vector_type(4)));

// ws layout (bf16 elements), FRAGMENT-LINEAR: chunk = tile*64 + lane, 8 elems/chunk.
#define WS_ENCW 0        // [nt8][kt8][lane][8]        -> 32768
#define WS_WIH  32768    // [nt8][g3][kt4][lane][8]    -> 49152
#define WS_WHH  81920    // [nt8][g3][kt4][lane][8]    -> 49152
#define WS_VW   131072   // [nt4][kt4][lane][8]        -> 8192
#define WS_DECW 139264   // [kt6][lane][8] (rows>=10 zero) -> 3072
#define WS_TOTC 17792    // total chunks (x64x8 elems = 142336)

__device__ __forceinline__ unsigned short f2bf(float f) {
    union { float f; unsigned int u; } v; v.f = f;
    unsigned int u = v.u;
    return (unsigned short)((u + 0x7fffu + ((u >> 16) & 1u)) >> 16);
}
// native cast -> hardware cvt (RNE, same rounding as manual)
__device__ __forceinline__ unsigned short f2bfn(float f) {
    union { __bf16 h; unsigned short s; } u; u.h = (__bf16)f;
    return u.s;
}
__device__ __forceinline__ float bf2f(unsigned short b) {
    union { unsigned int u; float f; } v; v.u = ((unsigned int)b) << 16;
    return v.f;
}
__device__ __forceinline__ float sigmf(float x) {
    x = fminf(fmaxf(x, -30.f), 30.f);
    return 1.f / (1.f + __expf(-x));
}
__device__ __forceinline__ float tanhfast(float x) {
    x = fminf(fmaxf(x, -15.f), 15.f);
    float e = __expf(2.f * x);
    return (e - 1.f) / (e + 1.f);
}

__device__ __forceinline__ bf16x8 cvt8g(const float* p) {
    float4 a = *reinterpret_cast<const float4*>(p);
    float4 b = *reinterpret_cast<const float4*>(p + 4);
    bf16x8 r;
    r[0] = (__bf16)a.x; r[1] = (__bf16)a.y; r[2] = (__bf16)a.z; r[3] = (__bf16)a.w;
    r[4] = (__bf16)b.x; r[5] = (__bf16)b.y; r[6] = (__bf16)b.z; r[7] = (__bf16)b.w;
    return r;
}
__device__ __forceinline__ bf16x8 ld8(const unsigned short* p) {
    return *reinterpret_cast<const bf16x8*>(p);
}

// async global->LDS, 16B per lane, no VGPR destination.
__device__ __forceinline__ void glds16(const unsigned short* g, unsigned short* l) {
    __builtin_amdgcn_global_load_lds(
        (const __attribute__((address_space(1))) unsigned int*)g,
        (__attribute__((address_space(3))) unsigned int*)l, 16, 0, 0);
}

// stage nfrags contiguous 1KB fragments; waves split the slots
__device__ __forceinline__ void stage_seq(unsigned short* dst, const unsigned short* src,
                                          int nfrags, int wave, int lane) {
    for (int s = wave; s < nfrags; s += 4)
        glds16(src + s * 512 + lane * 8, dst + s * 512);
}
// stage one GRU chunk ng = nt*3+g: slots 0..3 = w_ih kt0..3, slots 4..7 = w_hh kt0..3
__device__ __forceinline__ void stage_gru(unsigned short* dst, const unsigned short* wsw,
                                          int ng, int wave, int lane) {
    const int fo = (ng * 4 + wave) * 512 + lane * 8;
    glds16(wsw + WS_WIH + fo, dst + wave * 512);
    glds16(wsw + WS_WHH + fo, dst + (4 + wave) * 512);
}

// ---------- pre-kernel: f32 weights -> bf16 fragment-linear layout ----------
__global__ __launch_bounds__(256) void cvt_weights(
    const float* __restrict__ enc_w, const float* __restrict__ w_ih,
    const float* __restrict__ w_hh, const float* __restrict__ v_w,
    const float* __restrict__ dec_w, unsigned short* __restrict__ ws) {
    int c = blockIdx.x * 256 + threadIdx.x;
    if (c >= WS_TOTC) return;
    const int lane = c & 63;
    const int l = lane & 15;
    const int q = lane >> 4;
    const float* src; int row, col, stride; bool zero = false;
    if (c < 4096) {                      // enc_w [nt8][kt8]
        int lt = c >> 6; int nt = lt >> 3, kt = lt & 7;
        row = nt * 16 + l; col = kt * 32 + q * 8; src = enc_w; stride = 256;
    } else if (c < 10240) {              // w_ih [nt8][g3][kt4]
        int lt = (c - 4096) >> 6; int nt = lt / 12; int r2 = lt % 12;
        int g = r2 >> 2, kt = r2 & 3;
        row = g * 128 + nt * 16 + l; col = kt * 32 + q * 8; src = w_ih; stride = 128;
    } else if (c < 16384) {              // w_hh
        int lt = (c - 10240) >> 6; int nt = lt / 12; int r2 = lt % 12;
        int g = r2 >> 2, kt = r2 & 3;
        row = g * 128 + nt * 16 + l; col = kt * 32 + q * 8; src = w_hh; stride = 128;
    } else if (c < 17408) {              // v_w [nt4][kt4]
        int lt = (c - 16384) >> 6; int nt = lt >> 2, kt = lt & 3;
        row = nt * 16 + l; col = kt * 32 + q * 8; src = v_w; stride = 128;
    } else {                             // dec_w [kt6], zero-pad rows 10..15
        int kt = (c - 17408) >> 6;
        row = l; col = kt * 32 + q * 8; src = dec_w; stride = 192;
        zero = (l >= 10);
    }
    float4 a, b;
    if (zero) { a = make_float4(0.f,0.f,0.f,0.f); b = a; }
    else {
        const float* p = src + (size_t)row * stride + col;
        a = *reinterpret_cast<const float4*>(p);
        b = *reinterpret_cast<const float4*>(p + 4);
    }
    unsigned short* d = ws + (size_t)c * 8;
    d[0]=f2bf(a.x); d[1]=f2bf(a.y); d[2]=f2bf(a.z); d[3]=f2bf(a.w);
    d[4]=f2bf(b.x); d[5]=f2bf(b.y); d[6]=f2bf(b.z); d[7]=f2bf(b.w);
}

// ---------- main fused kernel: R2 staging skeleton at m=1, 4 blocks/CU ----------
// Tests occupancy ON the staged structure (R1's occupancy test was unstaged;
// R6/R7's attempts spilled via launch_bounds min-waves arg). m=1: 16 rows/wave,
// half the register state (R1: 64 VGPR) -> launch_bounds(256,4) caps 128 with
// no spill; LDS = 16KB ring + 17KB pool = 33.8KB -> 4 blocks/CU; grid 1024.
// 4 independent barrier-walks per CU interleave to hide each other's stage/
// barrier stalls. Chunk schedule & sync structure byte-identical to R2.
// Native __bf16 casts (R7 idea, unconfounded now).
__global__ __launch_bounds__(256, 4) void attn_critic_kernel(
    const float* __restrict__ obs,    // [SIZE,256] f32
    const float* __restrict__ hid,    // [SIZE,128] f32
    const float* __restrict__ enc_b,  // [128] f32
    const float* __restrict__ b_ih,   // [384] f32
    const float* __restrict__ b_hh,   // [384] f32
    const float* __restrict__ v_b,    // [64] f32
    const float* __restrict__ dec_b,  // [10] f32
    const unsigned short* __restrict__ wsw,  // bf16 fragment-linear weights
    float* __restrict__ out)          // [SIZE*10] ++ [SIZE*128] f32
{
    // weight ring: 2 x 8KB (8 fragment slots each)
    __shared__ __align__(16) unsigned short wbuf[2][4096];
    // per-wave pool: sA [16][136]; sV [16][72] + sO overlay after h_out stored
    __shared__ __align__(16) unsigned short pool[4][2176];

    const int tid  = threadIdx.x;
    const int wave = tid >> 6;
    const int lane = tid & 63;
    const int l15  = lane & 15;
    const int quad = lane >> 4;
    const int wrow0 = (blockIdx.x * 4 + wave) * 16;

    unsigned short (*sA)[136] = (unsigned short(*)[136])&pool[wave][0];  // [16][136]
    unsigned short (*sV)[72]  = (unsigned short(*)[72]) &pool[wave][0];  // [16][72] overlay
    float* sO = (float*)&pool[wave][1152];                               // [16][10] overlay

    int rA0 = wrow0 + l15; rA0 = (rA0 < SIZE) ? rA0 : (SIZE - 1);

    // ---- stage phase-1 chunk 0; latency hides under the prefetch ----
    stage_seq(wbuf[0], wsw + WS_ENCW, 8, wave, lane);

    // ---- prefetch obs + hid A-fragments ----
    bf16x8 aob[8], hf[4];
    {
        const float* o0 = obs + (size_t)rA0 * 256;
#pragma unroll
        for (int kt = 0; kt < 8; ++kt)
            aob[kt] = cvt8g(o0 + kt * 32 + quad * 8);
        const float* h0 = hid + (size_t)rA0 * 128;
#pragma unroll
        for (int kt = 0; kt < 4; ++kt)
            hf[kt] = cvt8g(h0 + kt * 32 + quad * 8);
    }
    __builtin_amdgcn_sched_barrier(0);
    __syncthreads();   // chunk 0 staged

    // ---- Phase 1: X = relu(OBS @ enc_w^T + enc_b), chunks 0..7 ----
#pragma unroll 1
    for (int nt = 0; nt < 8; ++nt) {
        const int cur = nt & 1;
        if (nt < 7) stage_seq(wbuf[cur ^ 1], wsw + WS_ENCW + (nt + 1) * 4096, 8, wave, lane);
        else        stage_gru(wbuf[cur ^ 1], wsw, 0, wave, lane);   // phase-2 chunk 0
        const float bias = enc_b[nt * 16 + l15];
        floatx4 a0 = floatx4{0.f,0.f,0.f,0.f};
#pragma unroll
        for (int kt = 0; kt < 8; ++kt) {
            bf16x8 b = ld8(&wbuf[cur][kt * 512 + lane * 8]);
            a0 = __builtin_amdgcn_mfma_f32_16x16x32_bf16(aob[kt], b, a0, 0, 0, 0);
        }
#pragma unroll
        for (int r = 0; r < 4; ++r)
            sA[quad * 4 + r][nt * 16 + l15] = f2bfn(fmaxf(a0[r] + bias, 0.f));
        __syncthreads();   // staged chunk ready; all reads of wbuf[cur] done
    }

    bf16x8 xf[4];
#pragma unroll
    for (int kt = 0; kt < 4; ++kt)
        xf[kt] = ld8(&sA[l15][kt * 32 + quad * 8]);

    // ---- Phase 2: GRU cell (h_out bf16 -> sA), chunks ng=0..23 ----
#pragma unroll 1
    for (int nt = 0; nt < 8; ++nt) {
        const int nr = nt * 16 + l15;
        float hp[4];
#pragma unroll
        for (int r = 0; r < 4; ++r) {
            const int grow = wrow0 + quad * 4 + r;
            const int rowc = (grow < SIZE) ? grow : (SIZE - 1);
            hp[r] = hid[(size_t)rowc * 128 + nr];
        }
        const float bir_ = b_ih[nr], biz_ = b_ih[nr + 128], bin_ = b_ih[nr + 256];
        const float bhr_ = b_hh[nr], bhz_ = b_hh[nr + 128], bhn_ = b_hh[nr + 256];
        floatx4 gi[3], gh[3];
#pragma unroll
        for (int g = 0; g < 3; ++g) {
            gi[g] = floatx4{0.f,0.f,0.f,0.f};
            gh[g] = gi[g];
        }
#pragma unroll
        for (int g = 0; g < 3; ++g) {
            const int cur = (nt + g) & 1;
            const int ng = nt * 3 + g + 1;
            if (ng < 24) stage_gru(wbuf[cur ^ 1], wsw, ng, wave, lane);
            else         stage_seq(wbuf[cur ^ 1], wsw + WS_VW, 4, wave, lane); // phase-3 chunk 0
#pragma unroll
            for (int kt = 0; kt < 4; ++kt) {
                bf16x8 bi = ld8(&wbuf[cur][kt * 512 + lane * 8]);
                bf16x8 bh = ld8(&wbuf[cur][(4 + kt) * 512 + lane * 8]);
                gi[g] = __builtin_amdgcn_mfma_f32_16x16x32_bf16(xf[kt], bi, gi[g], 0, 0, 0);
                gh[g] = __builtin_amdgcn_mfma_f32_16x16x32_bf16(hf[kt], bh, gh[g], 0, 0, 0);
            }
            __syncthreads();
        }
#pragma unroll
        for (int r = 0; r < 4; ++r) {
            float rg = sigmf(gi[0][r] + bir_ + gh[0][r] + bhr_);
            float zg = sigmf(gi[1][r] + biz_ + gh[1][r] + bhz_);
            float ng2 = tanhfast(gi[2][r] + bin_ + rg * (gh[2][r] + bhn_));
            float ho = (1.f - zg) * ng2 + zg * hp[r];
            sA[quad * 4 + r][nr] = f2bfn(ho);
        }
    }

    // ---- capture h_out fragments, store h_out (sA dies; sV/sO overlay) ----
    bf16x8 af[4];
#pragma unroll
    for (int kt = 0; kt < 4; ++kt)
        af[kt] = ld8(&sA[l15][kt * 32 + quad * 8]);
    {
        float* out_h = out + (size_t)SIZE * 10;
#pragma unroll 1
        for (int it = 0; it < 8; ++it) {
            int idx = it * 256 + lane * 4;   // over [16][128]
            int rr = idx >> 7, cc = idx & 127;
            int grow = wrow0 + rr;
            if (grow < SIZE) {
                float2 p0 = make_float2(bf2f(sA[rr][cc]),     bf2f(sA[rr][cc + 1]));
                float2 p1 = make_float2(bf2f(sA[rr][cc + 2]), bf2f(sA[rr][cc + 3]));
                float* dst = out_h + (size_t)grow * 128 + cc;
                *reinterpret_cast<float2*>(dst)     = p0;
                *reinterpret_cast<float2*>(dst + 2) = p1;
            }
        }
    }

    // ---- Phase 3: V = relu(H_OUT @ v_w^T + v_b) -> sV (overlay), chunks 0..3 ----
#pragma unroll 1
    for (int nt = 0; nt < 4; ++nt) {
        const int cur = nt & 1;
        if (nt < 3) stage_seq(wbuf[cur ^ 1], wsw + WS_VW + (nt + 1) * 2048, 4, wave, lane);
        else        stage_seq(wbuf[cur ^ 1], wsw + WS_DECW, 6, wave, lane);  // phase-4 chunk
        const float bias = v_b[nt * 16 + l15];
        floatx4 a0 = floatx4{0.f,0.f,0.f,0.f};
#pragma unroll
        for (int kt = 0; kt < 4; ++kt) {
            bf16x8 b = ld8(&wbuf[cur][kt * 512 + lane * 8]);
            a0 = __builtin_amdgcn_mfma_f32_16x16x32_bf16(af[kt], b, a0, 0, 0, 0);
        }
#pragma unroll
        for (int r = 0; r < 4; ++r)
            sV[quad * 4 + r][nt * 16 + l15] = f2bfn(fmaxf(a0[r] + bias, 0.f));
        __syncthreads();
    }

    // ---- Phase 4: OUT = [H_OUT|V] @ dec_w^T + dec_b (weights in wbuf[0]) ----
    {
        floatx4 d0 = floatx4{0.f,0.f,0.f,0.f};
#pragma unroll
        for (int kt = 0; kt < 6; ++kt) {
            bf16x8 b = ld8(&wbuf[0][kt * 512 + lane * 8]);
            bf16x8 a0 = (kt < 4) ? af[kt] : ld8(&sV[l15][(kt - 4) * 32 + quad * 8]);
            d0 = __builtin_amdgcn_mfma_f32_16x16x32_bf16(a0, b, d0, 0, 0, 0);
        }
        if (l15 < 10) {
            const float bias = dec_b[l15];
#pragma unroll
            for (int r = 0; r < 4; ++r)
                sO[(quad * 4 + r) * 10 + l15] = d0[r] + bias;
        }
        // coalesced store: 160 consecutive f32 per wave
#pragma unroll
        for (int j = 0; j < 3; ++j) {
            int idx = j * 64 + lane;          // 0..191, use 0..159
            if (idx < 160) {
                int row = idx / 10, col = idx % 10;
                int grow = wrow0 + row;
                if (grow < SIZE)
                    out[(size_t)grow * 10 + col] = sO[row * 10 + col];
            }
        }
    }
}

extern "C" void kernel_launch(void* const* d_in, const int* in_sizes, int n_in,
                              void* d_out, int out_size, void* d_ws, size_t ws_size,
                              hipStream_t stream) {
    const float* obs   = (const float*)d_in[0];
    const float* hid   = (const float*)d_in[1];
    const float* enc_w = (const float*)d_in[2];
    const float* enc_b = (const float*)d_in[3];
    const float* w_ih  = (const float*)d_in[4];
    const float* w_hh  = (const float*)d_in[5];
    const float* b_ih  = (const float*)d_in[6];
    const float* b_hh  = (const float*)d_in[7];
    // d_in[8..19]: dead code (bi-GRU / hard attention / q,k) — unused.
    const float* v_w   = (const float*)d_in[20];
    const float* v_b   = (const float*)d_in[21];
    const float* dec_w = (const float*)d_in[22];
    const float* dec_b = (const float*)d_in[23];
    unsigned short* wsw = (unsigned short*)d_ws;
    float* out = (float*)d_out;

    hipLaunchKernelGGL(cvt_weights, dim3((WS_TOTC + 255) / 256), dim3(256), 0, stream,
                       enc_w, w_ih, w_hh, v_w, dec_w, wsw);
    // 1024 blocks x 4 waves x 16 rows = 65536 >= 65535; 4 blocks/CU resident
    hipLaunchKernelGGL(attn_critic_kernel, dim3(1024), dim3(256), 0, stream,
                       obs, hid, enc_b, b_ih, b_hh, v_b, dec_b, wsw, out);
}